// Round 4
// baseline (1657575.781 us; speedup 1.0000x reference)
//
#include <hip/hip_runtime.h>
#include <stdint.h>

typedef __attribute__((ext_vector_type(8))) __bf16 bf16x8;
typedef __attribute__((ext_vector_type(4))) float f32x4;
typedef __attribute__((ext_vector_type(4))) unsigned u32x4;

#define DEVI static __device__ __forceinline__
#define SENT 0xFFFFFFFFu

DEVI bf16x8 bzero8(){ bf16x8 r;
#pragma unroll
  for (int i=0;i<8;++i) r[i]=(__bf16)0.0f; return r; }

DEVI bf16x8 ld8(const __bf16* p){ return *(const bf16x8*)p; }
DEVI void st8(__bf16* p, bf16x8 v){ *(bf16x8*)p = v; }

DEVI f32x4 MFMA(bf16x8 a, bf16x8 b, f32x4 c){
  return __builtin_amdgcn_mfma_f32_16x16x32_bf16(a, b, c, 0, 0, 0);
}

DEVI float sigf(float x){ return 1.0f/(1.0f+__expf(-x)); }

// ---- agent-scope (MALL) relaxed atomics ----
DEVI unsigned ald(const unsigned* p){ return __hip_atomic_load(p, __ATOMIC_RELAXED, __HIP_MEMORY_SCOPE_AGENT); }
DEVI void ast(unsigned* p, unsigned v){ __hip_atomic_store(p, v, __ATOMIC_RELAXED, __HIP_MEMORY_SCOPE_AGENT); }

// dual store: plain (lands in local XCD L2, visible to sc0 loads) + agent
// (writes through to MALL, backs the deep-fallback path)
DEVI void dualst(unsigned* p, unsigned v){
  *((volatile unsigned*)p) = v;
  __hip_atomic_store(p, v, __ATOMIC_RELAXED, __HIP_MEMORY_SCOPE_AGENT);
}

DEVI unsigned packbf(float a, float b){
  union { __bf16 h[2]; unsigned u; } x; x.h[0]=(__bf16)a; x.h[1]=(__bf16)b; return x.u;
}
DEVI float bflo(unsigned u){ return __builtin_bit_cast(float, u<<16); }
DEVI float bfhi(unsigned u){ return __builtin_bit_cast(float, u & 0xffff0000u); }
DEVI unsigned s4bad(u32x4 a){
  return (unsigned)((a[0]==SENT)|(a[1]==SENT)|(a[2]==SENT)|(a[3]==SENT));
}

// ---- XCD-local polling loads: sc0 = SE scope (bypass L1, hit local L2) ----
#define POLL16_ASM(F) \
  asm volatile( \
    "global_load_dwordx4 %0, %16, off " F "\n\t" \
    "global_load_dwordx4 %1, %16, off offset:64 " F "\n\t" \
    "global_load_dwordx4 %2, %16, off offset:128 " F "\n\t" \
    "global_load_dwordx4 %3, %16, off offset:192 " F "\n\t" \
    "global_load_dwordx4 %4, %16, off offset:256 " F "\n\t" \
    "global_load_dwordx4 %5, %16, off offset:320 " F "\n\t" \
    "global_load_dwordx4 %6, %16, off offset:384 " F "\n\t" \
    "global_load_dwordx4 %7, %16, off offset:448 " F "\n\t" \
    "global_load_dwordx4 %8, %16, off offset:512 " F "\n\t" \
    "global_load_dwordx4 %9, %16, off offset:576 " F "\n\t" \
    "global_load_dwordx4 %10, %16, off offset:640 " F "\n\t" \
    "global_load_dwordx4 %11, %16, off offset:704 " F "\n\t" \
    "global_load_dwordx4 %12, %16, off offset:768 " F "\n\t" \
    "global_load_dwordx4 %13, %16, off offset:832 " F "\n\t" \
    "global_load_dwordx4 %14, %16, off offset:896 " F "\n\t" \
    "global_load_dwordx4 %15, %16, off offset:960 " F "\n\t" \
    "s_waitcnt vmcnt(0)" \
    : "=&v"(v0),"=&v"(v1),"=&v"(v2),"=&v"(v3),"=&v"(v4),"=&v"(v5),"=&v"(v6),"=&v"(v7), \
      "=&v"(v8),"=&v"(v9),"=&v"(v10),"=&v"(v11),"=&v"(v12),"=&v"(v13),"=&v"(v14),"=&v"(v15) \
    : "v"(p) : "memory")

DEVI void poll16(const void* p, bf16x8 af[16]){
  u32x4 v0,v1,v2,v3,v4,v5,v6,v7,v8,v9,v10,v11,v12,v13,v14,v15;
  int tries = 0;
  for (;;){
    if (tries < 4096){ POLL16_ASM("sc0"); } else { POLL16_ASM("sc0 sc1"); }
    unsigned bad = s4bad(v0)|s4bad(v1)|s4bad(v2)|s4bad(v3)|s4bad(v4)|s4bad(v5)|s4bad(v6)|s4bad(v7)
                 | s4bad(v8)|s4bad(v9)|s4bad(v10)|s4bad(v11)|s4bad(v12)|s4bad(v13)|s4bad(v14)|s4bad(v15);
    if (!bad) break;
    ++tries;
  }
  af[0]=__builtin_bit_cast(bf16x8,v0);  af[1]=__builtin_bit_cast(bf16x8,v1);
  af[2]=__builtin_bit_cast(bf16x8,v2);  af[3]=__builtin_bit_cast(bf16x8,v3);
  af[4]=__builtin_bit_cast(bf16x8,v4);  af[5]=__builtin_bit_cast(bf16x8,v5);
  af[6]=__builtin_bit_cast(bf16x8,v6);  af[7]=__builtin_bit_cast(bf16x8,v7);
  af[8]=__builtin_bit_cast(bf16x8,v8);  af[9]=__builtin_bit_cast(bf16x8,v9);
  af[10]=__builtin_bit_cast(bf16x8,v10); af[11]=__builtin_bit_cast(bf16x8,v11);
  af[12]=__builtin_bit_cast(bf16x8,v12); af[13]=__builtin_bit_cast(bf16x8,v13);
  af[14]=__builtin_bit_cast(bf16x8,v14); af[15]=__builtin_bit_cast(bf16x8,v15);
}

#define POLL2_ASM(F) \
  asm volatile( \
    "global_load_dwordx4 %0, %2, off " F "\n\t" \
    "global_load_dwordx4 %1, %2, off offset:16 " F "\n\t" \
    "s_waitcnt vmcnt(0)" \
    : "=&v"(q0), "=&v"(q1) : "v"(p) : "memory")

DEVI void poll2(const void* p, u32x4& o0, u32x4& o1){
  u32x4 q0, q1;
  int tries = 0;
  for (;;){
    if (tries < 4096){ POLL2_ASM("sc0"); } else { POLL2_ASM("sc0 sc1"); }
    if (!(s4bad(q0)|s4bad(q1))) break;
    ++tries;
  }
  o0 = q0; o1 = q1;
}

// ---- XCD election: claim a slot on this block's XCD; first two XCDs to
// claim get roles 1 and 2. e: [0]=order, [1..8]=claim, [9..16]=role ----
DEVI void elect(unsigned* e, int* shp){
  if (threadIdx.x == 0){
    unsigned x;
    asm volatile("s_getreg_b32 %0, hwreg(HW_REG_XCC_ID)" : "=s"(x));
    x &= 7u;
    unsigned s = __hip_atomic_fetch_add(e + 1 + x, 1u, __ATOMIC_RELAXED, __HIP_MEMORY_SCOPE_AGENT);
    if (s == 0u){
      unsigned o = __hip_atomic_fetch_add(e, 1u, __ATOMIC_RELAXED, __HIP_MEMORY_SCOPE_AGENT);
      ast(e + 9 + x, o + 1u);
    }
    unsigned r;
    while ((r = ald(e + 9 + x)) == 0u) __builtin_amdgcn_s_sleep(1);
    shp[0] = (int)s; shp[1] = (int)r;
  }
  __syncthreads();
}

// ---- flag barrier (init use only) ----
DEVI void flagbar(unsigned* slots, int nblk, int bk, unsigned ep){
  __syncthreads();
  asm volatile("" ::: "memory");
  if (threadIdx.x == 0) ast(slots + (size_t)bk*16, ep);
  if ((int)threadIdx.x < nblk){
    const unsigned* sp = slots + (size_t)threadIdx.x*16;
    while (ald(sp) < ep) __builtin_amdgcn_s_sleep(1);
  }
  asm volatile("" ::: "memory");
  __syncthreads();
}

// ---------------- packing ----------------
DEVI void packGroup(const float* W, int Nsrc, int Kreal, int NT, __bf16* dst, long g){
  int kt = (int)(g / (NT*64));
  int rem = (int)(g % (NT*64));
  int nt = rem >> 6, ln = rem & 63;
  int row = nt*16 + (ln & 15);
  int col = kt*32 + ((ln >> 4) << 3);
  bf16x8 v = bzero8();
  if (row < Nsrc){
#pragma unroll
    for (int j=0;j<8;++j){ int c = col + j; if (c < Kreal) v[j] = (__bf16)W[(long)row*Kreal + c]; }
  }
  st8(dst + g*8, v);
}

DEVI void packGroupCat(const float* Wih, const float* Whh, __bf16* dst, long g){
  int kt = (int)(g / (128*64));
  int rem = (int)(g % (128*64));
  int nt = rem >> 6, ln = rem & 63;
  int prow = nt*16 + (ln & 15);
  int src = (prow & 3)*512 + (prow >> 2);
  int col = kt*32 + ((ln >> 4) << 3);
  bf16x8 v;
  if (col < 32){
#pragma unroll
    for (int j=0;j<8;++j) v[j] = (__bf16)Wih[(long)src*32 + col + j];
  } else {
#pragma unroll
    for (int j=0;j<8;++j) v[j] = (__bf16)Whh[(long)src*512 + (col-32) + j];
  }
  st8(dst + g*8, v);
}

__global__ void initK(unsigned* bar, unsigned* hb, unsigned* ctx, unsigned* xb){
  int g = blockIdx.x*256 + threadIdx.x;
  if (g < 3072){ bar[g] = 0u; return; }   // flag slots + election regions
  g -= 3072;
  if (g < 6144){ hb[2048 + g] = SENT; return; }   // HB bufs 1..3 (buf0 = h0b)
  g -= 6144;
  if (g < 8192){ ctx[g] = SENT; return; }         // CTXB all 4 bufs
  g -= 8192;
  if (g < 4096){ xb[g] = SENT; return; }          // XB all 4 bufs
}

__global__ void packSmallK(const float* __restrict__ xs, const float* __restrict__ eWih,
    const float* __restrict__ eWhh, const float* __restrict__ ebih, const float* __restrict__ ebhh,
    const float* __restrict__ attnW, const float* __restrict__ combW,
    __bf16* __restrict__ xsb, __bf16* __restrict__ wcatp, float* __restrict__ biasc,
    __bf16* __restrict__ attnp, __bf16* __restrict__ combp)
{
  long g = (long)blockIdx.x*blockDim.x + threadIdx.x;
  const long nWcat = 17L*128*64;
  const long nXs   = 92160;
  const long nBias = 2048;
  const long nAttn = 33L*2*64;
  const long nComb = 33L*32*64;
  if (g < nWcat){ packGroupCat(eWih, eWhh, wcatp, g); return; }
  g -= nWcat;
  if (g < nXs){
    const float* s = xs + g*8; bf16x8 v;
#pragma unroll
    for (int j=0;j<8;++j) v[j] = (__bf16)s[j];
    st8(xsb + g*8, v); return;
  }
  g -= nXs;
  if (g < nBias){ int src = ((int)g & 3)*512 + ((int)g >> 2); biasc[g] = ebih[src] + ebhh[src]; return; }
  g -= nBias;
  if (g < nAttn){ packGroup(attnW, 30, 1032, 2, attnp, g); return; }
  g -= nAttn;
  if (g < nComb){ packGroup(combW, 512, 1032, 32, combp, g); return; }
}

__global__ void packPencK(const float* __restrict__ Wf, const float* __restrict__ Wb,
    const float* __restrict__ bihf, const float* __restrict__ bhhf,
    const float* __restrict__ bihb, const float* __restrict__ bhhb,
    __bf16* __restrict__ pf, __bf16* __restrict__ pb, float* __restrict__ bsum)
{
  long g = (long)blockIdx.x*blockDim.x + threadIdx.x;
  const long nW = 64L*128*64;
  if (g < nW){ packGroup(Wf, 2048, 2048, 128, pf, g); return; }
  g -= nW;
  if (g < nW){ packGroup(Wb, 2048, 2048, 128, pb, g); return; }
  g -= nW;
  if (g < 2048){ bsum[g] = bihf[g] + bhhf[g]; return; }
  g -= 2048;
  if (g < 2048){ bsum[2048+g] = bihb[g] + bhhb[g]; return; }
}

// ---------------- encoder step ----------------
__global__ __launch_bounds__(256, 1) void encStepK(
    const __bf16* __restrict__ xsb,
    __bf16* __restrict__ henc,
    float* __restrict__ cenc,
    const __bf16* __restrict__ wcatp,
    const float* __restrict__ biasc,
    const int* __restrict__ xlen,
    __bf16* __restrict__ ctx,
    int t)
{
  __shared__ float glds[64][260];
  const int tid = threadIdx.x;
  const int w = tid >> 6, ln = tid & 63;
  const int m0 = blockIdx.x * 64;
  const int nb = blockIdx.y;
  f32x4 acc[16];
#pragma unroll
  for (int i=0;i<16;++i) acc[i] = (f32x4){0.f,0.f,0.f,0.f};

  const int arow = m0 + w*16 + (ln & 15);
  const int kc = (ln >> 4) << 3;
  const int ktEnd = (t == 0) ? 1 : 17;
  for (int kt = 0; kt < ktEnd; ++kt){
    bf16x8 a;
    if (kt == 0) a = ld8(xsb + ((long)t*1920 + arow)*32 + kc);
    else         a = ld8(henc + (long)arow*512 + (kt-1)*32 + kc);
    const __bf16* bp = wcatp + (((long)kt*128 + nb*16)*64 + ln)*8;
#pragma unroll
    for (int n2 = 0; n2 < 16; ++n2){
      bf16x8 b = ld8(bp + (long)n2*512);
      acc[n2] = MFMA(a, b, acc[n2]);
    }
  }
  const int r4 = (ln >> 4) << 2;
#pragma unroll
  for (int n2 = 0; n2 < 16; ++n2){
#pragma unroll
    for (int r = 0; r < 4; ++r)
      glds[w*16 + r4 + r][n2*16 + (ln & 15)] = acc[n2][r];
  }
  __syncthreads();
  for (int it = 0; it < 16; ++it){
    int idx = tid + it*256;
    int mrow = idx >> 6, hcl = idx & 63;
    int n = m0 + mrow;
    int hcg = nb*64 + hcl;
    float ig = glds[mrow][hcl*4+0] + biasc[nb*256 + hcl*4+0];
    float fg = glds[mrow][hcl*4+1] + biasc[nb*256 + hcl*4+1];
    float gg = glds[mrow][hcl*4+2] + biasc[nb*256 + hcl*4+2];
    float og = glds[mrow][hcl*4+3] + biasc[nb*256 + hcl*4+3];
    float c_old = (t == 0) ? 0.0f : cenc[(long)n*512 + hcg];
    float cn = sigf(fg)*c_old + sigf(ig)*tanhf(gg);
    float h  = sigf(og)*tanhf(cn);
    cenc[(long)n*512 + hcg] = cn;
    henc[(long)n*512 + hcg] = (__bf16)h;
    if (xlen[n] - 1 == t){
      ctx[(long)n*1024 + hcg]       = (__bf16)h;
      ctx[(long)n*1024 + 512 + hcg] = (__bf16)cn;
    }
  }
}

// ---------------- pyramid input GEMM ----------------
__global__ __launch_bounds__(1024) void pencInK(
   const __bf16* __restrict__ inb,
   const __bf16* __restrict__ wpf, const __bf16* __restrict__ wpb,
   const float* __restrict__ bsum,
   float* __restrict__ xpf, float* __restrict__ xpb,
   int M)
{
  const int tid = threadIdx.x, ln = tid & 63, wv = tid >> 6;
  const int rg = wv >> 2, cg = wv & 3;
  const int dir = blockIdx.z;
  const int m0 = blockIdx.x*64 + rg*16;
  const int nb = blockIdx.y;
  const __bf16* wp = dir ? wpb : wpf;
  float* xp = dir ? xpb : xpf;
  const float* bs = bsum + dir*2048;
  f32x4 acc[4];
#pragma unroll
  for (int i=0;i<4;++i) acc[i] = (f32x4){0.f,0.f,0.f,0.f};
  const int arow = m0 + (ln & 15);
  const int kc = (ln >> 4) << 3;
  const bool aok = arow < M;
  for (int kt = 0; kt < 64; ++kt){
    bf16x8 a = aok ? ld8(inb + (long)arow*2048 + kt*32 + kc) : bzero8();
    const __bf16* bp = wp + (((long)kt*128 + nb*16 + cg*4)*64 + ln)*8;
#pragma unroll
    for (int q = 0; q < 4; ++q){
      bf16x8 b = ld8(bp + (long)q*512);
      acc[q] = MFMA(a, b, acc[q]);
    }
  }
  const int r4 = (ln >> 4) << 2;
#pragma unroll
  for (int q = 0; q < 4; ++q){
    int col = (nb*16 + cg*4 + q)*16 + (ln & 15);
#pragma unroll
    for (int r = 0; r < 4; ++r){
      int rowo = m0 + r4 + r;
      if (rowo < M) xp[(long)rowo*2048 + col] = acc[q][r] + bs[col];
    }
  }
}

// ---------------- pyramid recurrence: persistent, XCD-local h exchange ----------------
// 256 blocks launched; 16 fwd workers on one XCD, 16 bwd on another.
__global__ __launch_bounds__(256, 1) void pyrRecK(
  const float* __restrict__ WhhF, const float* __restrict__ WhhB,
  const float* __restrict__ xpf, const float* __restrict__ xpb,
  __bf16* __restrict__ hbuf,        // [2dir][4buf][4][512]
  __bf16* __restrict__ outb,
  float* __restrict__ outf,
  float* __restrict__ h0f, __bf16* __restrict__ h0b,
  unsigned* __restrict__ slotsF, unsigned* __restrict__ slotsB,
  unsigned* __restrict__ elec,
  int T, int isLast)
{
  __shared__ __align__(16) __bf16 WL[128*512];
  __shared__ float glds[4][4][32];
  __shared__ int eSh[2];
  const int tid = threadIdx.x, ln = tid & 63, w = tid >> 6;

  elect(elec, eSh);
  const int slot = eSh[0], role = eSh[1];
  if (!((role == 1 || role == 2) && slot < 16)) return;
  const int dir = role - 1;
  const int hc0 = slot * 32;
  const float* Whh = dir ? WhhB : WhhF;
  const float* xp  = dir ? xpb : xpf;
  unsigned* slots = dir ? slotsB : slotsF;
  unsigned* hbu = (unsigned*)hbuf;

  for (int it = 0; it < 32; ++it){
    int g = it*256 + tid;
    int rho = g >> 6, c8 = g & 63;
    int gate = rho >> 5, hcl = rho & 31;
    const float* src = Whh + ((long)(gate*512 + hc0 + hcl))*512 + c8*8;
    bf16x8 v;
#pragma unroll
    for (int j=0;j<8;++j) v[j] = (__bf16)src[j];
    int off = (rho*1024 + c8*16) ^ ((rho & 7) << 4);
    st8((__bf16*)((char*)WL + off), v);
  }
  // init own h cols: buf0 = 0, bufs 1..3 = sentinel
  if (tid < 128 && !(tid & 1)){
    int b = tid >> 5, hcl = tid & 31;
    int base = (hc0 + hcl) >> 1;
#pragma unroll
    for (int bu = 0; bu < 4; ++bu)
      dualst(hbu + ((size_t)(dir*4 + bu)*4 + b)*256 + base, bu == 0 ? 0u : SENT);
  }
  flagbar(slots, 16, slot, 1);

  float cv = 0.0f;
  const int arow = ln & 15;
  const int kc = (ln >> 4) << 3;
  const int rho0 = w*32 + (ln & 15);
  const int rho1 = rho0 + 16;
  for (int t = 0; t < T; ++t){
    int cur = t & 3, nxt = (t+1) & 3, clr = (t+2) & 3;
    int pos = dir ? (T-1-t) : t;
    float x0=0.f, x1=0.f, x2=0.f, x3=0.f;
    if (tid < 128){
      const float* xr = xp + ((long)((tid>>5)*T + pos))*2048 + hc0 + (tid & 31);
      x0 = xr[0]; x1 = xr[512]; x2 = xr[1024]; x3 = xr[1536];
    }
    // re-sentinel buffer t+2 (own cols); drained before produce via syncthreads/vmcnt
    if (tid < 128 && !(tid & 1)){
      int b = tid >> 5, hcl = tid & 31;
      dualst(hbu + ((size_t)(dir*4 + clr)*4 + b)*256 + ((hc0 + hcl) >> 1), SENT);
    }
    // poll h(t) fragments into registers (XCD-local L2)
    bf16x8 af[16];
    if (arow < 4){
      const __bf16* hsrc = hbuf + ((size_t)(dir*4 + cur)*4 + arow)*512 + kc;
      poll16(hsrc, af);
    } else {
#pragma unroll
      for (int kt = 0; kt < 16; ++kt) af[kt] = bzero8();
    }
    f32x4 a0 = {0.f,0.f,0.f,0.f}, a1 = {0.f,0.f,0.f,0.f};
#pragma unroll
    for (int kt = 0; kt < 16; ++kt){
      int k2 = (kt*32 + kc)*2;
      bf16x8 b0 = ld8((__bf16*)((char*)WL + ((rho0*1024 + k2) ^ ((rho0 & 7) << 4))));
      bf16x8 b1 = ld8((__bf16*)((char*)WL + ((rho1*1024 + k2) ^ ((rho1 & 7) << 4))));
      a0 = MFMA(af[kt], b0, a0);
      a1 = MFMA(af[kt], b1, a1);
    }
    __syncthreads();
    if (ln < 16){
#pragma unroll
      for (int r=0;r<4;++r){ glds[w][r][ln] = a0[r]; glds[w][r][16+ln] = a1[r]; }
    }
    __syncthreads();
    if (tid < 128){
      int b = tid >> 5, hcl = tid & 31, hcg = hc0 + hcl;
      float ig = glds[0][b][hcl] + x0;
      float fg = glds[1][b][hcl] + x1;
      float gg = glds[2][b][hcl] + x2;
      float og = glds[3][b][hcl] + x3;
      cv = sigf(fg)*cv + sigf(ig)*tanhf(gg);
      float h = sigf(og)*tanhf(cv);
      float hn = __shfl_down(h, 1);
      if (!(hcl & 1))
        dualst(hbu + ((size_t)(dir*4 + nxt)*4 + b)*256 + (hcg >> 1), packbf(h, hn));
      if (!isLast){
        outb[((long)(b*T + pos))*1024 + dir*512 + hcg] = (__bf16)h;
      } else {
        outf[((long)(b*T + pos))*1024 + dir*512 + hcg] = h;
        if (t == T-1){
          h0f[b*1024 + dir*512 + hcg] = h;
          h0b[b*1024 + dir*512 + hcg] = (__bf16)h;
        }
      }
    }
  }
}

// ---------------- decoder: persistent, 32 workers on ONE XCD ----------------
DEVI bf16x8 dfrag(const __bf16* base, const __bf16* inp, int row, int kt, int kc, int stride){
  if (row >= 4) return bzero8();
  int k = kt*32 + kc;
  if (k == 0) return ld8(inp + row*8);
  int off = k - 8;
  return (off < 1024) ? ld8(base + row*stride + off) : bzero8();
}

__global__ __launch_bounds__(256, 1) void decoderK(
  const float* __restrict__ gWih,   // [3072][512]
  const float* __restrict__ gWhh,   // [3072][1024]
  const float* __restrict__ gbih, const float* __restrict__ gbhh,
  const float* __restrict__ combBias, const float* __restrict__ attnBias,
  const float* __restrict__ outW, const float* __restrict__ outBias,
  const __bf16* __restrict__ attnP, const __bf16* __restrict__ combP,
  const float* __restrict__ encOut,  // [4][30][1024] f32
  const float* __restrict__ h0f,
  __bf16* __restrict__ HB,           // [4buf][4][1024]
  __bf16* __restrict__ CTXB,         // [4buf][4][1024]
  __bf16* __restrict__ XB,           // [4buf][4][512]
  float* __restrict__ dout,
  unsigned* __restrict__ elec)
{
  __shared__ __align__(16) __bf16 giL[96*512];     // 96 KB (forces 1 block/CU)
  __shared__ __align__(16) __bf16 outWL[8*1024];
  __shared__ __align__(16) __bf16 hL[4*1024];
  __shared__ __align__(16) __bf16 ctxvL[4][1056];
  __shared__ __bf16 encOutL[4][30][32];
  __shared__ __align__(16) __bf16 inpL[32];
  __shared__ float awL[4][30];
  __shared__ float redL[4][8];
  __shared__ float ghL[3][4][32];
  __shared__ float giO[3][4][32];
  __shared__ float combL[4][4][16];
  __shared__ float biL[3][32], bhL[3][32];
  __shared__ float abL[30], cbL[16];
  __shared__ int eSh[2];

  const int tid = threadIdx.x, ln = tid & 63, w = tid >> 6;
  elect(elec, eSh);
  const int slot = eSh[0], role = eSh[1];
  if (!(role == 1 && slot < 32)) return;
  const int hc0 = slot * 32;
  unsigned* HBu = (unsigned*)HB;
  unsigned* CTXu = (unsigned*)CTXB;
  unsigned* XBu = (unsigned*)XB;

  // gi weights -> LDS (96 rows x 512, bf16, XOR swizzled)
  for (int it = 0; it < 24; ++it){
    int g = it*256 + tid;
    int rho = g >> 6, c8 = g & 63;
    int gate = rho >> 5, r = rho & 31;
    const float* s = gWih + ((long)(gate*1024 + hc0 + r))*512 + c8*8;
    bf16x8 v;
#pragma unroll
    for (int j=0;j<8;++j) v[j] = (__bf16)s[j];
    st8((__bf16*)((char*)giL + ((rho*1024 + c8*16) ^ ((rho & 7) << 4))), v);
  }
  for (int it = 0; it < 32; ++it){
    int g = it*256 + tid;
    outWL[g] = (__bf16)outW[g];
  }
  for (int idx = tid; idx < 3840; idx += 256){
    int b = idx/960, rem = idx%960;
    int t2 = rem >> 5, dl = rem & 31;
    encOutL[b][t2][dl] = (__bf16)encOut[((long)b*30 + t2)*1024 + hc0 + dl];
  }
  if (tid < 96){
    int g2 = tid >> 5, l = tid & 31;
    biL[g2][l] = gbih[g2*1024 + hc0 + l];
    bhL[g2][l] = gbhh[g2*1024 + hc0 + l];
  }
  if (tid < 30) abL[tid] = attnBias[tid];
  if (tid < 16) cbL[tid] = combBias[slot*16 + tid];

  const int row = ln & 15, kc = (ln >> 4) << 3;
  // bigF: w0 -> attn frags [2x33]; w1-3 -> gh frags for gate w-1 [2x32]
  bf16x8 bigF[66];
  if (w == 0){
#pragma unroll
    for (int nt = 0; nt < 2; ++nt)
#pragma unroll
      for (int kt = 0; kt < 33; ++kt)
        bigF[nt*33 + kt] = ld8(attnP + (((size_t)kt*2 + nt)*64 + ln)*8);
  } else {
    int gate = w - 1;
#pragma unroll
    for (int nt = 0; nt < 2; ++nt)
#pragma unroll
      for (int kt = 0; kt < 32; ++kt){
        const float* s = gWhh + ((long)(gate*1024 + hc0 + nt*16 + row))*1024 + kt*32 + kc;
        bf16x8 v;
#pragma unroll
        for (int j=0;j<8;++j) v[j] = (__bf16)s[j];
        bigF[nt*33 + kt] = v;   // note: nt*33 spacing (unused slot at kt=32)
      }
  }
  const int kt0c = (w == 0) ? 0 : (w*8 + 1);
  const int nkt = (w == 0) ? 9 : 8;
  bf16x8 combF[9];
#pragma unroll
  for (int i = 0; i < 9; ++i)
    combF[i] = (i < nkt) ? ld8(combP + (((size_t)(kt0c+i)*32 + slot)*64 + ln)*8) : bzero8();

  float hold = 0.f;
  if (tid < 128) hold = h0f[(tid>>5)*1024 + hc0 + (tid & 31)];
  __syncthreads();

  for (int s = 0; s <= 32; ++s){
    int cur = s & 3, nxt = (s+1) & 3, clr = (s+2) & 3;
    // re-sentinel step s+2 buffers (own cols)
    if (tid < 64){
      int b = tid >> 4, i = tid & 15;
      dualst(HBu  + ((size_t)clr*4 + b)*512 + (hc0 >> 1) + i, SENT);
      dualst(CTXu + ((size_t)clr*4 + b)*512 + (hc0 >> 1) + i, SENT);
    }
    if (tid < 32){
      int b = tid >> 3, i = tid & 7;
      dualst(XBu + ((size_t)clr*4 + b)*256 + ((slot*16) >> 1) + i, SENT);
    }
    // poll h(s) -> hL (32B per thread)
    {
      u32x4 q0, q1;
      poll2((const char*)HB + (size_t)cur*8192 + tid*32, q0, q1);
      ((u32x4*)hL)[tid*2]   = q0;
      ((u32x4*)hL)[tid*2+1] = q1;
    }
    __syncthreads();
    if (s == 0){
      if (tid < 32) inpL[tid] = (__bf16)0.0f;
      __syncthreads();
    } else {
      int o = tid >> 3, sl = tid & 7;
      int b = o >> 3, l = o & 7;
      const unsigned* hlp = (const unsigned*)hL + b*512 + sl*64;
      const unsigned* wlp = (const unsigned*)outWL + l*512 + sl*64;
      float p = 0.f;
      for (int kk = 0; kk < 64; ++kk){
        unsigned u = hlp[kk], t2 = wlp[kk];
        p += bflo(u)*bflo(t2) + bfhi(u)*bfhi(t2);
      }
      p += __shfl_down(p, 4);
      p += __shfl_down(p, 2);
      p += __shfl_down(p, 1);
      if (sl == 0) redL[b][l] = p + outBias[l];
      __syncthreads();
      if (tid < 4){
        float m = redL[tid][0];
        for (int l2=1;l2<8;++l2) m = fmaxf(m, redL[tid][l2]);
        float sum = 0.f;
        for (int l2=0;l2<8;++l2) sum += __expf(redL[tid][l2]-m);
        float lse = m + __logf(sum);
        for (int l2=0;l2<8;++l2){
          float lp = redL[tid][l2] - lse;
          inpL[tid*8 + l2] = (__bf16)lp;
          if (slot == 0) dout[((long)tid*32 + (s-1))*8 + l2] = lp;
        }
      }
      __syncthreads();
    }
    if (s == 32) break;

    // P1: w0 attn logits; w1-3 gh (gate w-1), B in registers
    if (w == 0){
      f32x4 a0 = {0.f,0.f,0.f,0.f}, a1 = {0.f,0.f,0.f,0.f};
#pragma unroll
      for (int kt = 0; kt < 33; ++kt){
        bf16x8 a = dfrag(hL, inpL, row, kt, kc, 1024);
        a0 = MFMA(a, bigF[kt], a0);
        a1 = MFMA(a, bigF[33+kt], a1);
      }
      if (ln < 16){
#pragma unroll
        for (int r=0;r<4;++r) awL[r][ln] = a0[r] + abL[ln];
        if (16 + ln < 30){
#pragma unroll
          for (int r=0;r<4;++r) awL[r][16+ln] = a1[r] + abL[16+ln];
        }
      }
    } else {
      f32x4 a0 = {0.f,0.f,0.f,0.f}, a1 = {0.f,0.f,0.f,0.f};
#pragma unroll
      for (int kt = 0; kt < 32; ++kt){
        int k = kt*32 + kc;
        bf16x8 a = (row < 4) ? ld8(hL + row*1024 + k) : bzero8();
        a0 = MFMA(a, bigF[kt], a0);
        a1 = MFMA(a, bigF[33+kt], a1);
      }
      if (ln < 16){
        int gate = w - 1;
#pragma unroll
        for (int r=0;r<4;++r){
          ghL[gate][r][ln] = a0[r];
          ghL[gate][r][16+ln] = a1[r];
        }
      }
    }
    __syncthreads();
    if (tid < 4){
      float m = awL[tid][0];
      for (int t2=1;t2<30;++t2) m = fmaxf(m, awL[tid][t2]);
      float sum = 0.f;
      for (int t2=0;t2<30;++t2){ float e = __expf(awL[tid][t2]-m); awL[tid][t2] = e; sum += e; }
      float inv = 1.0f/sum;
      for (int t2=0;t2<30;++t2) awL[tid][t2] *= inv;
    }
    __syncthreads();
    // produce ctxv (own 32 cols)
    if (tid < 128){
      int b = tid >> 5, dl = tid & 31;
      float sum = 0.f;
      for (int t2=0;t2<30;++t2) sum += awL[b][t2]*(float)encOutL[b][t2][dl];
      float sn = __shfl_down(sum, 1);
      if (!(dl & 1))
        dualst(CTXu + ((size_t)cur*4 + b)*512 + ((hc0 + dl) >> 1), packbf(sum, sn));
    }
    // poll full ctxv -> ctxvL
    {
      u32x4 q0, q1;
      poll2((const char*)CTXB + (size_t)cur*8192 + tid*32, q0, q1);
      u32x4* dst = (u32x4*)((char*)&ctxvL[0][0] + (tid>>6)*2112 + (tid&63)*32);
      dst[0] = q0; dst[1] = q1;
    }
    __syncthreads();
    // P2: comb (16 out cols), K split across 4 waves
    {
      f32x4 acc = {0.f,0.f,0.f,0.f};
#pragma unroll
      for (int i = 0; i < 9; ++i){
        if (i < nkt){
          bf16x8 a = dfrag(&ctxvL[0][0], inpL, row, kt0c+i, kc, 1056);
          acc = MFMA(a, combF[i], acc);
        }
      }
      if (ln < 16){
#pragma unroll
        for (int r=0;r<4;++r) combL[w][r][ln] = acc[r];
      }
    }
    __syncthreads();
    if (tid < 64){
      int r = tid >> 4, l = tid & 15, col = slot*16 + l;
      float x = combL[0][r][l] + combL[1][r][l] + combL[2][r][l] + combL[3][r][l] + cbL[l];
      x = fmaxf(x, 0.0f);
      float xn = __shfl_down(x, 1);
      if (!(l & 1))
        dualst(XBu + ((size_t)cur*4 + r)*256 + (col >> 1), packbf(x, xn));
    }
    // P3: w1-3 poll x, gi MFMA (B from LDS giL)
    if (w >= 1){
      int gate = w - 1;
      bf16x8 xf[16];
      if (row < 4){
        poll16((const char*)XB + (size_t)cur*4096 + row*1024 + kc*2, xf);
      } else {
#pragma unroll
        for (int kt = 0; kt < 16; ++kt) xf[kt] = bzero8();
      }
      f32x4 a0 = {0.f,0.f,0.f,0.f}, a1 = {0.f,0.f,0.f,0.f};
#pragma unroll
      for (int kt = 0; kt < 16; ++kt){
        int k = kt*32 + kc;
        int rho0 = gate*32 + row, rho1 = rho0 + 16;
        bf16x8 b0 = ld8((__bf16*)((char*)giL + ((rho0*1024 + k*2) ^ ((rho0 & 7) << 4))));
        bf16x8 b1 = ld8((__bf16*)((char*)giL + ((rho1*1024 + k*2) ^ ((rho1 & 7) << 4))));
        a0 = MFMA(xf[kt], b0, a0);
        a1 = MFMA(xf[kt], b1, a1);
      }
      if (ln < 16){
#pragma unroll
        for (int r=0;r<4;++r){
          giO[gate][r][ln] = a0[r] + biL[gate][ln];
          giO[gate][r][16+ln] = a1[r] + biL[gate][16+ln];
        }
      }
    }
    __syncthreads();
    // GRU cell (own 32 cols)
    if (tid < 128){
      int b = tid >> 5, l = tid & 31, hcg = hc0 + l;
      float rr = sigf(giO[0][b][l] + ghL[0][b][l] + bhL[0][l]);
      float zz = sigf(giO[1][b][l] + ghL[1][b][l] + bhL[1][l]);
      float nn = tanhf(giO[2][b][l] + rr*(ghL[2][b][l] + bhL[2][l]));
      float hnew = (1.0f - zz)*nn + zz*hold;
      hold = hnew;
      float h2 = __shfl_down(hnew, 1);
      if (!(l & 1))
        dualst(HBu + ((size_t)nxt*4 + b)*512 + (hcg >> 1), packbf(hnew, h2));
    }
  }
}

// ---------------- host ----------------
static const size_t O_BAR   = 0;          // 8KB flag slots + elections (12KB total)
static const size_t O_XSB   = 12288;
static const size_t O_WCATP = 1486848;
static const size_t O_BIASC = 3715072;
static const size_t O_HENC  = 3723264;
static const size_t O_CENC  = 5689344;
static const size_t O_CTX   = 9621504;
static const size_t O_WIHPF = 13553664;
static const size_t O_WIHPB = 21942272;
static const size_t O_BSUM  = 30330880;
static const size_t O_XPF   = 30347264;
static const size_t O_XPB   = 38211584;
static const size_t O_HPYR  = 46075904;
static const size_t O_OUTA  = 46108672;
static const size_t O_OUTB  = 48074752;
static const size_t O_ENCO  = 49057792;
static const size_t O_H0F   = 49549312;
static const size_t O_HB    = 49565696;
static const size_t O_CTXB  = 49598464;
static const size_t O_XB    = 49631232;
static const size_t O_ATTNP = 49647616;
static const size_t O_COMBP = 49715200;
// end 50796544 (~48.4 MiB)

extern "C" void kernel_launch(void* const* d_in, const int* in_sizes, int n_in,
                              void* d_out, int out_size, void* d_ws, size_t ws_size,
                              hipStream_t stream)
{
  const float* xs    = (const float*)d_in[0];
  const int*   xlen  = (const int*)d_in[1];
  const float* eWih  = (const float*)d_in[2];
  const float* eWhh  = (const float*)d_in[3];
  const float* ebih  = (const float*)d_in[4];
  const float* ebhh  = (const float*)d_in[5];
  const float* pWihF = (const float*)d_in[6];
  const float* pWhhF = (const float*)d_in[7];
  const float* pbihF = (const float*)d_in[8];
  const float* pbhhF = (const float*)d_in[9];
  const float* pWihB = (const float*)d_in[10];
  const float* pWhhB = (const float*)d_in[11];
  const float* pbihB = (const float*)d_in[12];
  const float* pbhhB = (const float*)d_in[13];
  const float* attnW = (const float*)d_in[14];
  const float* attnb = (const float*)d_in[15];
  const float* combW = (const float*)d_in[16];
  const float* combb = (const float*)d_in[17];
  const float* gWih  = (const float*)d_in[18];
  const float* gWhh  = (const float*)d_in[19];
  const float* gbih  = (const float*)d_in[20];
  const float* gbhh  = (const float*)d_in[21];
  const float* outW  = (const float*)d_in[22];
  const float* outb  = (const float*)d_in[23];

  char* ws = (char*)d_ws;
  unsigned* BARU  = (unsigned*)(ws + O_BAR);
  __bf16* XSB     = (__bf16*)(ws + O_XSB);
  __bf16* WCATP   = (__bf16*)(ws + O_WCATP);
  float*  BIASC   = (float*)(ws + O_BIASC);
  __bf16* HENC    = (__bf16*)(ws + O_HENC);
  float*  CENC    = (float*)(ws + O_CENC);
  __bf16* CTX     = (__bf16*)(ws + O_CTX);
  __bf16* WIHPF   = (__bf16*)(ws + O_WIHPF);
  __bf16* WIHPB   = (__bf16*)(ws + O_WIHPB);
  float*  BSUM    = (float*)(ws + O_BSUM);
  float*  XPF     = (float*)(ws + O_XPF);
  float*  XPB     = (float*)(ws + O_XPB);
  __bf16* HPYR    = (__bf16*)(ws + O_HPYR);
  __bf16* OUTA    = (__bf16*)(ws + O_OUTA);
  __bf16* OUTB    = (__bf16*)(ws + O_OUTB);
  float*  ENCO    = (float*)(ws + O_ENCO);
  float*  H0F     = (float*)(ws + O_H0F);
  __bf16* HB      = (__bf16*)(ws + O_HB);
  __bf16* CTXB    = (__bf16*)(ws + O_CTXB);
  __bf16* XB      = (__bf16*)(ws + O_XB);
  __bf16* ATTNP   = (__bf16*)(ws + O_ATTNP);
  __bf16* COMBP   = (__bf16*)(ws + O_COMBP);

  initK<<<84, 256, 0, stream>>>(BARU, (unsigned*)HB, (unsigned*)CTXB, (unsigned*)XB);
  packSmallK<<<1193, 256, 0, stream>>>(xs, eWih, eWhh, ebih, ebhh, attnW, combW,
      XSB, WCATP, BIASC, ATTNP, COMBP);

  for (int t = 0; t < 12; ++t)
    encStepK<<<dim3(30, 8), 256, 0, stream>>>(XSB, HENC, CENC, WCATP, BIASC, xlen, CTX, t);

  const int Ts[4] = {240, 120, 60, 30};
  const __bf16* ins[4] = {CTX, OUTA, OUTB, OUTA};
  __bf16* outs[4] = {OUTA, OUTB, OUTA, OUTB};
  for (int L = 0; L < 4; ++L){
    int T = Ts[L];
    packPencK<<<4113, 256, 0, stream>>>(pWihF + (long)L*2048*2048, pWihB + (long)L*2048*2048,
        pbihF + L*2048, pbhhF + L*2048, pbihB + L*2048, pbhhB + L*2048,
        WIHPF, WIHPB, BSUM);
    int MB = (4*T + 63)/64;
    pencInK<<<dim3(MB, 8, 2), 1024, 0, stream>>>(ins[L], WIHPF, WIHPB, BSUM, XPF, XPB, 4*T);
    pyrRecK<<<256, 256, 0, stream>>>(pWhhF + (long)L*2048*512, pWhhB + (long)L*2048*512,
        XPF, XPB, HPYR, outs[L], ENCO, H0F, HB,
        BARU + (size_t)(L*2+0)*256, BARU + (size_t)(L*2+1)*256,
        BARU + 2048 + (size_t)L*32, T, (L==3) ? 1 : 0);
  }

  decoderK<<<256, 256, 0, stream>>>(gWih, gWhh, gbih, gbhh, combb, attnb, outW, outb,
      ATTNP, COMBP, ENCO, H0F, HB, CTXB, XB, (float*)d_out,
      BARU + 2048 + 4*32);
}

// Round 5
// 2256.179 us; speedup vs baseline: 734.6827x; 734.6827x over previous
//
#include <hip/hip_runtime.h>
#include <stdint.h>

typedef __attribute__((ext_vector_type(8))) __bf16 bf16x8;
typedef __attribute__((ext_vector_type(4))) float f32x4;
typedef __attribute__((ext_vector_type(4))) unsigned u32x4;

#define DEVI static __device__ __forceinline__
#define SENT 0xFFFFFFFFu

DEVI bf16x8 bzero8(){ bf16x8 r;
#pragma unroll
  for (int i=0;i<8;++i) r[i]=(__bf16)0.0f; return r; }

DEVI bf16x8 ld8(const __bf16* p){ return *(const bf16x8*)p; }
DEVI void st8(__bf16* p, bf16x8 v){ *(bf16x8*)p = v; }

DEVI f32x4 MFMA(bf16x8 a, bf16x8 b, f32x4 c){
  return __builtin_amdgcn_mfma_f32_16x16x32_bf16(a, b, c, 0, 0, 0);
}

DEVI float sigf(float x){ return 1.0f/(1.0f+__expf(-x)); }

// ---- agent-scope (MALL) relaxed atomics ----
DEVI void ast(unsigned* p, unsigned v){ __hip_atomic_store(p, v, __ATOMIC_RELAXED, __HIP_MEMORY_SCOPE_AGENT); }

DEVI unsigned packbf(float a, float b){
  union { __bf16 h[2]; unsigned u; } x; x.h[0]=(__bf16)a; x.h[1]=(__bf16)b; return x.u;
}
DEVI float bflo(unsigned u){ return __builtin_bit_cast(float, u<<16); }
DEVI float bfhi(unsigned u){ return __builtin_bit_cast(float, u & 0xffff0000u); }

DEVI unsigned bad4(u32x4 v){ return (v[0]==SENT)|(v[1]==SENT)|(v[2]==SENT)|(v[3]==SENT); }

// agent-coherent 16B load (bypass L1+L2, read MALL)
DEVI u32x4 ald4(const void* p){
  u32x4 v;
  asm volatile("global_load_dwordx4 %0, %1, off sc0 sc1\n\ts_waitcnt vmcnt(0)"
               : "=&v"(v) : "v"(p) : "memory");
  return v;
}
DEVI u32x4 poll4(const void* p){
  u32x4 v = ald4(p);
  while (bad4(v)){ __builtin_amdgcn_s_sleep(1); v = ald4(p); }
  return v;
}
DEVI void ald4x2(const void* p, u32x4& a, u32x4& b){
  asm volatile("global_load_dwordx4 %0, %2, off sc0 sc1\n\t"
               "global_load_dwordx4 %1, %2, off offset:16 sc0 sc1\n\t"
               "s_waitcnt vmcnt(0)"
               : "=&v"(a), "=&v"(b) : "v"(p) : "memory");
}
DEVI void poll4x2(const void* p, u32x4& a, u32x4& b){
  ald4x2(p, a, b);
  while (bad4(a) | bad4(b)){ __builtin_amdgcn_s_sleep(1); ald4x2(p, a, b); }
}

// ---------------- packing ----------------
DEVI void packGroup(const float* W, int Nsrc, int Kreal, int NT, __bf16* dst, long g){
  int kt = (int)(g / (NT*64));
  int rem = (int)(g % (NT*64));
  int nt = rem >> 6, ln = rem & 63;
  int row = nt*16 + (ln & 15);
  int col = kt*32 + ((ln >> 4) << 3);
  bf16x8 v = bzero8();
  if (row < Nsrc){
#pragma unroll
    for (int j=0;j<8;++j){ int c = col + j; if (c < Kreal) v[j] = (__bf16)W[(long)row*Kreal + c]; }
  }
  st8(dst + g*8, v);
}

DEVI void packGroupCat(const float* Wih, const float* Whh, __bf16* dst, long g){
  int kt = (int)(g / (128*64));
  int rem = (int)(g % (128*64));
  int nt = rem >> 6, ln = rem & 63;
  int prow = nt*16 + (ln & 15);
  int src = (prow & 3)*512 + (prow >> 2);
  int col = kt*32 + ((ln >> 4) << 3);
  bf16x8 v;
  if (col < 32){
#pragma unroll
    for (int j=0;j<8;++j) v[j] = (__bf16)Wih[(long)src*32 + col + j];
  } else {
#pragma unroll
    for (int j=0;j<8;++j) v[j] = (__bf16)Whh[(long)src*512 + (col-32) + j];
  }
  st8(dst + g*8, v);
}

// sentinel decoder comm buffers
__global__ void initK(unsigned* bar, unsigned* hb, unsigned* ctx, unsigned* xb){
  int g = blockIdx.x*256 + threadIdx.x;
  if (g < 3072){ bar[g] = 0u; return; }
  g -= 3072;
  if (g < 6144){ hb[2048 + g] = SENT; return; }   // HB bufs 1..3 (buf0 = h0b)
  g -= 6144;
  if (g < 8192){ ctx[g] = SENT; return; }
  g -= 8192;
  if (g < 4096){ xb[g] = SENT; return; }
}

__global__ void packSmallK(const float* __restrict__ xs, const float* __restrict__ eWih,
    const float* __restrict__ eWhh, const float* __restrict__ ebih, const float* __restrict__ ebhh,
    const float* __restrict__ attnW, const float* __restrict__ combW,
    __bf16* __restrict__ xsb, __bf16* __restrict__ wcatp, float* __restrict__ biasc,
    __bf16* __restrict__ attnp, __bf16* __restrict__ combp)
{
  long g = (long)blockIdx.x*blockDim.x + threadIdx.x;
  const long nWcat = 17L*128*64;
  const long nXs   = 92160;
  const long nBias = 2048;
  const long nAttn = 33L*2*64;
  const long nComb = 33L*32*64;
  if (g < nWcat){ packGroupCat(eWih, eWhh, wcatp, g); return; }
  g -= nWcat;
  if (g < nXs){
    const float* s = xs + g*8; bf16x8 v;
#pragma unroll
    for (int j=0;j<8;++j) v[j] = (__bf16)s[j];
    st8(xsb + g*8, v); return;
  }
  g -= nXs;
  if (g < nBias){ int src = ((int)g & 3)*512 + ((int)g >> 2); biasc[g] = ebih[src] + ebhh[src]; return; }
  g -= nBias;
  if (g < nAttn){ packGroup(attnW, 30, 1032, 2, attnp, g); return; }
  g -= nAttn;
  if (g < nComb){ packGroup(combW, 512, 1032, 32, combp, g); return; }
}

// pack pyramid layer weights + re-init this layer's HPYR rotation buffers
__global__ void packPencK(const float* __restrict__ Wf, const float* __restrict__ Wb,
    const float* __restrict__ bihf, const float* __restrict__ bhhf,
    const float* __restrict__ bihb, const float* __restrict__ bhhb,
    __bf16* __restrict__ pf, __bf16* __restrict__ pb, float* __restrict__ bsum,
    unsigned* __restrict__ hpy)
{
  long g = (long)blockIdx.x*blockDim.x + threadIdx.x;
  const long nW = 64L*128*64;
  if (g < nW){ packGroup(Wf, 2048, 2048, 128, pf, g); return; }
  g -= nW;
  if (g < nW){ packGroup(Wb, 2048, 2048, 128, pb, g); return; }
  g -= nW;
  if (g < 2048){ bsum[g] = bihf[g] + bhhf[g]; return; }
  g -= 2048;
  if (g < 2048){ bsum[2048+g] = bihb[g] + bhhb[g]; return; }
  g -= 2048;
  if (g < 8192){  // [2dir][4buf][4][512] bf16 = 8192 dwords; buf0=0, bufs1-3=SENT
    hpy[g] = ((g >> 10) & 3) ? SENT : 0u;
  }
}

// ---------------- encoder step ----------------
__global__ __launch_bounds__(256, 1) void encStepK(
    const __bf16* __restrict__ xsb,
    __bf16* __restrict__ henc,
    float* __restrict__ cenc,
    const __bf16* __restrict__ wcatp,
    const float* __restrict__ biasc,
    const int* __restrict__ xlen,
    __bf16* __restrict__ ctx,
    int t)
{
  __shared__ float glds[64][260];
  const int tid = threadIdx.x;
  const int w = tid >> 6, ln = tid & 63;
  const int m0 = blockIdx.x * 64;
  const int nb = blockIdx.y;
  f32x4 acc[16];
#pragma unroll
  for (int i=0;i<16;++i) acc[i] = (f32x4){0.f,0.f,0.f,0.f};

  const int arow = m0 + w*16 + (ln & 15);
  const int kc = (ln >> 4) << 3;
  const int ktEnd = (t == 0) ? 1 : 17;
  for (int kt = 0; kt < ktEnd; ++kt){
    bf16x8 a;
    if (kt == 0) a = ld8(xsb + ((long)t*1920 + arow)*32 + kc);
    else         a = ld8(henc + (long)arow*512 + (kt-1)*32 + kc);
    const __bf16* bp = wcatp + (((long)kt*128 + nb*16)*64 + ln)*8;
#pragma unroll
    for (int n2 = 0; n2 < 16; ++n2){
      bf16x8 b = ld8(bp + (long)n2*512);
      acc[n2] = MFMA(a, b, acc[n2]);
    }
  }
  const int r4 = (ln >> 4) << 2;
#pragma unroll
  for (int n2 = 0; n2 < 16; ++n2){
#pragma unroll
    for (int r = 0; r < 4; ++r)
      glds[w*16 + r4 + r][n2*16 + (ln & 15)] = acc[n2][r];
  }
  __syncthreads();
  for (int it = 0; it < 16; ++it){
    int idx = tid + it*256;
    int mrow = idx >> 6, hcl = idx & 63;
    int n = m0 + mrow;
    int hcg = nb*64 + hcl;
    float ig = glds[mrow][hcl*4+0] + biasc[nb*256 + hcl*4+0];
    float fg = glds[mrow][hcl*4+1] + biasc[nb*256 + hcl*4+1];
    float gg = glds[mrow][hcl*4+2] + biasc[nb*256 + hcl*4+2];
    float og = glds[mrow][hcl*4+3] + biasc[nb*256 + hcl*4+3];
    float c_old = (t == 0) ? 0.0f : cenc[(long)n*512 + hcg];
    float cn = sigf(fg)*c_old + sigf(ig)*tanhf(gg);
    float h  = sigf(og)*tanhf(cn);
    cenc[(long)n*512 + hcg] = cn;
    henc[(long)n*512 + hcg] = (__bf16)h;
    if (xlen[n] - 1 == t){
      ctx[(long)n*1024 + hcg]       = (__bf16)h;
      ctx[(long)n*1024 + 512 + hcg] = (__bf16)cn;
    }
  }
}

// ---------------- pyramid input GEMM ----------------
__global__ __launch_bounds__(1024) void pencInK(
   const __bf16* __restrict__ inb,
   const __bf16* __restrict__ wpf, const __bf16* __restrict__ wpb,
   const float* __restrict__ bsum,
   float* __restrict__ xpf, float* __restrict__ xpb,
   int M)
{
  const int tid = threadIdx.x, ln = tid & 63, wv = tid >> 6;
  const int rg = wv >> 2, cg = wv & 3;
  const int dir = blockIdx.z;
  const int m0 = blockIdx.x*64 + rg*16;
  const int nb = blockIdx.y;
  const __bf16* wp = dir ? wpb : wpf;
  float* xp = dir ? xpb : xpf;
  const float* bs = bsum + dir*2048;
  f32x4 acc[4];
#pragma unroll
  for (int i=0;i<4;++i) acc[i] = (f32x4){0.f,0.f,0.f,0.f};
  const int arow = m0 + (ln & 15);
  const int kc = (ln >> 4) << 3;
  const bool aok = arow < M;
  for (int kt = 0; kt < 64; ++kt){
    bf16x8 a = aok ? ld8(inb + (long)arow*2048 + kt*32 + kc) : bzero8();
    const __bf16* bp = wp + (((long)kt*128 + nb*16 + cg*4)*64 + ln)*8;
#pragma unroll
    for (int q = 0; q < 4; ++q){
      bf16x8 b = ld8(bp + (long)q*512);
      acc[q] = MFMA(a, b, acc[q]);
    }
  }
  const int r4 = (ln >> 4) << 2;
#pragma unroll
  for (int q = 0; q < 4; ++q){
    int col = (nb*16 + cg*4 + q)*16 + (ln & 15);
#pragma unroll
    for (int r = 0; r < 4; ++r){
      int rowo = m0 + r4 + r;
      if (rowo < M) xp[(long)rowo*2048 + col] = acc[q][r] + bs[col];
    }
  }
}

// ---------------- pyramid recurrence: persistent, sentinel data-poll ----------------
// 32 blocks: [0..15]=fwd, [16..31]=bwd; hbuf = this layer's [2dir][4buf][4][512]
__global__ __launch_bounds__(256, 1) void pyrRecK(
  const float* __restrict__ WhhF, const float* __restrict__ WhhB,
  const float* __restrict__ xpf, const float* __restrict__ xpb,
  __bf16* __restrict__ hbuf,
  __bf16* __restrict__ outb,
  float* __restrict__ outf,
  float* __restrict__ h0f, __bf16* __restrict__ h0b,
  int T, int isLast)
{
  __shared__ __align__(16) __bf16 WL[128*512];
  __shared__ __align__(16) __bf16 hsL[4*512];
  __shared__ float glds[4][4][32];
  const int tid = threadIdx.x, ln = tid & 63, w = tid >> 6;
  const int bk = blockIdx.x;
  const int dir = bk >> 4, slot = bk & 15;
  const int hc0 = slot * 32;
  const float* Whh = dir ? WhhB : WhhF;
  const float* xp  = dir ? xpb : xpf;
  unsigned* hbu = (unsigned*)hbuf;

  for (int it = 0; it < 32; ++it){
    int g = it*256 + tid;
    int rho = g >> 6, c8 = g & 63;
    int gate = rho >> 5, hcl = rho & 31;
    const float* src = Whh + ((long)(gate*512 + hc0 + hcl))*512 + c8*8;
    bf16x8 v;
#pragma unroll
    for (int j=0;j<8;++j) v[j] = (__bf16)src[j];
    int off = (rho*1024 + c8*16) ^ ((rho & 7) << 4);
    st8((__bf16*)((char*)WL + off), v);
  }

  float cv = 0.0f;
  const int arow = ln & 15;
  const int kc = (ln >> 4) << 3;
  const int rho0 = w*32 + (ln & 15);
  const int rho1 = rho0 + 16;
  for (int t = 0; t < T; ++t){
    int cur = t & 3, nxt = (t+1) & 3, clr = (t+2) & 3;
    int pos = dir ? (T-1-t) : t;
    // prefetch cell inputs (independent of h)
    float x0=0.f, x1=0.f, x2=0.f, x3=0.f;
    if (tid < 128){
      const float* xr = xp + ((long)((tid>>5)*T + pos))*2048 + hc0 + (tid & 31);
      x0 = xr[0]; x1 = xr[512]; x2 = xr[1024]; x3 = xr[1536];
    }
    // re-sentinel buffer t+2 (own cols); safe: depth-4 + poll-gated skew < 1 step
    if (tid < 128 && !(tid & 1)){
      int b = tid >> 5, hcl = tid & 31;
      ast(hbu + ((size_t)(dir*4 + clr)*4 + b)*256 + ((hc0 + hcl) >> 1), SENT);
    }
    // batched poll h(t) -> LDS (256 threads x 16B = 4KB)
    {
      u32x4 v = poll4((const char*)hbuf + (size_t)(dir*4 + cur)*4096 + tid*16);
      ((u32x4*)hsL)[tid] = v;
    }
    __syncthreads();
    f32x4 a0 = {0.f,0.f,0.f,0.f}, a1 = {0.f,0.f,0.f,0.f};
#pragma unroll
    for (int kt = 0; kt < 16; ++kt){
      bf16x8 a = (arow < 4) ? ld8(hsL + arow*512 + kt*32 + kc) : bzero8();
      int k2 = (kt*32 + kc)*2;
      bf16x8 b0 = ld8((__bf16*)((char*)WL + ((rho0*1024 + k2) ^ ((rho0 & 7) << 4))));
      bf16x8 b1 = ld8((__bf16*)((char*)WL + ((rho1*1024 + k2) ^ ((rho1 & 7) << 4))));
      a0 = MFMA(a, b0, a0);
      a1 = MFMA(a, b1, a1);
    }
    __syncthreads();
    if (ln < 16){
#pragma unroll
      for (int r=0;r<4;++r){ glds[w][r][ln] = a0[r]; glds[w][r][16+ln] = a1[r]; }
    }
    __syncthreads();
    if (tid < 128){
      int b = tid >> 5, hcl = tid & 31, hcg = hc0 + hcl;
      float ig = glds[0][b][hcl] + x0;
      float fg = glds[1][b][hcl] + x1;
      float gg = glds[2][b][hcl] + x2;
      float og = glds[3][b][hcl] + x3;
      cv = sigf(fg)*cv + sigf(ig)*tanhf(gg);
      float h = sigf(og)*tanhf(cv);
      float hn = __shfl_down(h, 1);
      if (!(hcl & 1))
        ast(hbu + ((size_t)(dir*4 + nxt)*4 + b)*256 + (hcg >> 1), packbf(h, hn));
      if (!isLast){
        outb[((long)(b*T + pos))*1024 + dir*512 + hcg] = (__bf16)h;
      } else {
        outf[((long)(b*T + pos))*1024 + dir*512 + hcg] = h;
        if (t == T-1){
          h0f[b*1024 + dir*512 + hcg] = h;
          h0b[b*1024 + dir*512 + hcg] = (__bf16)h;
        }
      }
    }
  }
}

// ---------------- decoder: persistent, 32 blocks, sentinel data-poll ----------------
DEVI bf16x8 dfrag(const __bf16* base, const __bf16* inp, int row, int kt, int kc, int stride){
  if (row >= 4) return bzero8();
  int k = kt*32 + kc;
  if (k == 0) return ld8(inp + row*8);
  int off = k - 8;
  return (off < 1024) ? ld8(base + row*stride + off) : bzero8();
}

__global__ __launch_bounds__(256, 1) void decoderK(
  const float* __restrict__ gWih,   // [3072][512]
  const float* __restrict__ gWhh,   // [3072][1024]
  const float* __restrict__ gbih, const float* __restrict__ gbhh,
  const float* __restrict__ combBias, const float* __restrict__ attnBias,
  const float* __restrict__ outW, const float* __restrict__ outBias,
  const __bf16* __restrict__ attnP, const __bf16* __restrict__ combP,
  const float* __restrict__ encOut,  // [4][30][1024] f32
  const float* __restrict__ h0f,
  __bf16* __restrict__ HB,           // [4buf][4][1024]
  __bf16* __restrict__ CTXB,         // [4buf][4][1024]
  __bf16* __restrict__ XB,           // [4buf][4][512]
  float* __restrict__ dout)
{
  __shared__ __align__(16) __bf16 giL[96*512];     // 96 KB
  __shared__ __align__(16) __bf16 outWL[8*1024];
  __shared__ __align__(16) __bf16 hL[4*1024];
  __shared__ __align__(16) __bf16 ctxvL[4][1056];
  __shared__ __align__(16) __bf16 xL[4][528];
  __shared__ __bf16 encOutL[4][30][32];
  __shared__ __align__(16) __bf16 inpL[32];
  __shared__ float awL[4][30];
  __shared__ float redL[4][8];
  __shared__ float ghL[3][4][32];
  __shared__ float giO[3][4][32];
  __shared__ float combL[4][4][16];
  __shared__ float biL[3][32], bhL[3][32];
  __shared__ float abL[30], cbL[16];

  const int tid = threadIdx.x, ln = tid & 63, w = tid >> 6;
  const int slot = blockIdx.x;
  const int hc0 = slot * 32;
  unsigned* HBu = (unsigned*)HB;
  unsigned* CTXu = (unsigned*)CTXB;
  unsigned* XBu = (unsigned*)XB;

  // gi weights -> LDS (3 gates x 32 own cols = 96 rows x 512, XOR swizzled)
  for (int it = 0; it < 24; ++it){
    int g = it*256 + tid;
    int rho = g >> 6, c8 = g & 63;
    int gate = rho >> 5, r = rho & 31;
    const float* s = gWih + ((long)(gate*1024 + hc0 + r))*512 + c8*8;
    bf16x8 v;
#pragma unroll
    for (int j=0;j<8;++j) v[j] = (__bf16)s[j];
    st8((__bf16*)((char*)giL + ((rho*1024 + c8*16) ^ ((rho & 7) << 4))), v);
  }
  for (int it = 0; it < 32; ++it){
    int g = it*256 + tid;
    outWL[g] = (__bf16)outW[g];
  }
  for (int idx = tid; idx < 3840; idx += 256){
    int b = idx/960, rem = idx%960;
    int t2 = rem >> 5, dl = rem & 31;
    encOutL[b][t2][dl] = (__bf16)encOut[((long)b*30 + t2)*1024 + hc0 + dl];
  }
  if (tid < 96){
    int g2 = tid >> 5, l = tid & 31;
    biL[g2][l] = gbih[g2*1024 + hc0 + l];
    bhL[g2][l] = gbhh[g2*1024 + hc0 + l];
  }
  if (tid < 30) abL[tid] = attnBias[tid];
  if (tid < 16) cbL[tid] = combBias[slot*16 + tid];

  const int row = ln & 15, kc = (ln >> 4) << 3;
  // bigF: w0 -> attn frags [2x33]; w1-3 -> gh frags for gate w-1 [2x32]
  bf16x8 bigF[66];
  if (w == 0){
#pragma unroll
    for (int nt = 0; nt < 2; ++nt)
#pragma unroll
      for (int kt = 0; kt < 33; ++kt)
        bigF[nt*33 + kt] = ld8(attnP + (((size_t)kt*2 + nt)*64 + ln)*8);
  } else {
    int gate = w - 1;
#pragma unroll
    for (int nt = 0; nt < 2; ++nt)
#pragma unroll
      for (int kt = 0; kt < 32; ++kt){
        const float* s = gWhh + ((long)(gate*1024 + hc0 + nt*16 + row))*1024 + kt*32 + kc;
        bf16x8 v;
#pragma unroll
        for (int j=0;j<8;++j) v[j] = (__bf16)s[j];
        bigF[nt*33 + kt] = v;
      }
  }
  const int kt0c = (w == 0) ? 0 : (w*8 + 1);
  const int nkt = (w == 0) ? 9 : 8;
  bf16x8 combF[9];
#pragma unroll
  for (int i = 0; i < 9; ++i)
    combF[i] = (i < nkt) ? ld8(combP + (((size_t)(kt0c+i)*32 + slot)*64 + ln)*8) : bzero8();

  float hold = 0.f;
  if (tid < 128) hold = h0f[(tid>>5)*1024 + hc0 + (tid & 31)];
  __syncthreads();

  for (int s = 0; s <= 32; ++s){
    int cur = s & 3, nxt = (s+1) & 3, clr = (s+2) & 3;
    // re-sentinel step s+2 buffers (own cols)
    if (tid < 64){
      int b = tid >> 4, i = tid & 15;
      ast(HBu  + ((size_t)clr*4 + b)*512 + (hc0 >> 1) + i, SENT);
      ast(CTXu + ((size_t)clr*4 + b)*512 + (hc0 >> 1) + i, SENT);
    }
    if (tid < 32){
      int b = tid >> 3, i = tid & 7;
      ast(XBu + ((size_t)clr*4 + b)*256 + ((slot*16) >> 1) + i, SENT);
    }
    // batched poll h(s) -> hL (256 threads x 32B = 8KB)
    {
      u32x4 q0, q1;
      poll4x2((const char*)HB + (size_t)cur*8192 + tid*32, q0, q1);
      ((u32x4*)hL)[tid*2]   = q0;
      ((u32x4*)hL)[tid*2+1] = q1;
    }
    __syncthreads();
    if (s == 0){
      if (tid < 32) inpL[tid] = (__bf16)0.0f;
      __syncthreads();
    } else {
      int o = tid >> 3, sl = tid & 7;
      int b = o >> 3, l = o & 7;
      const unsigned* hlp = (const unsigned*)hL + b*512 + sl*64;
      const unsigned* wlp = (const unsigned*)outWL + l*512 + sl*64;
      float p = 0.f;
      for (int kk = 0; kk < 64; ++kk){
        unsigned u = hlp[kk], t2 = wlp[kk];
        p += bflo(u)*bflo(t2) + bfhi(u)*bfhi(t2);
      }
      p += __shfl_down(p, 4);
      p += __shfl_down(p, 2);
      p += __shfl_down(p, 1);
      if (sl == 0) redL[b][l] = p + outBias[l];
      __syncthreads();
      if (tid < 4){
        float m = redL[tid][0];
        for (int l2=1;l2<8;++l2) m = fmaxf(m, redL[tid][l2]);
        float sum = 0.f;
        for (int l2=0;l2<8;++l2) sum += __expf(redL[tid][l2]-m);
        float lse = m + __logf(sum);
        for (int l2=0;l2<8;++l2){
          float lp = redL[tid][l2] - lse;
          inpL[tid*8 + l2] = (__bf16)lp;
          if (slot == 0) dout[((long)tid*32 + (s-1))*8 + l2] = lp;
        }
      }
      __syncthreads();
    }
    if (s == 32) break;

    // P1: w0 attn logits; w1-3 gh (gate w-1), B in registers
    if (w == 0){
      f32x4 a0 = {0.f,0.f,0.f,0.f}, a1 = {0.f,0.f,0.f,0.f};
#pragma unroll
      for (int kt = 0; kt < 33; ++kt){
        bf16x8 a = dfrag(hL, inpL, row, kt, kc, 1024);
        a0 = MFMA(a, bigF[kt], a0);
        a1 = MFMA(a, bigF[33+kt], a1);
      }
      if (ln < 16){
#pragma unroll
        for (int r=0;r<4;++r) awL[r][ln] = a0[r] + abL[ln];
        if (16 + ln < 30){
#pragma unroll
          for (int r=0;r<4;++r) awL[r][16+ln] = a1[r] + abL[16+ln];
        }
      }
    } else {
      f32x4 a0 = {0.f,0.f,0.f,0.f}, a1 = {0.f,0.f,0.f,0.f};
#pragma unroll
      for (int kt = 0; kt < 32; ++kt){
        int k = kt*32 + kc;
        bf16x8 a = (row < 4) ? ld8(hL + row*1024 + k) : bzero8();
        a0 = MFMA(a, bigF[kt], a0);
        a1 = MFMA(a, bigF[33+kt], a1);
      }
      if (ln < 16){
        int gate = w - 1;
#pragma unroll
        for (int r=0;r<4;++r){
          ghL[gate][r][ln] = a0[r];
          ghL[gate][r][16+ln] = a1[r];
        }
      }
    }
    __syncthreads();
    if (tid < 4){
      float m = awL[tid][0];
      for (int t2=1;t2<30;++t2) m = fmaxf(m, awL[tid][t2]);
      float sum = 0.f;
      for (int t2=0;t2<30;++t2){ float e = __expf(awL[tid][t2]-m); awL[tid][t2] = e; sum += e; }
      float inv = 1.0f/sum;
      for (int t2=0;t2<30;++t2) awL[tid][t2] *= inv;
    }
    __syncthreads();
    // produce ctxv (own 32 cols)
    if (tid < 128){
      int b = tid >> 5, dl = tid & 31;
      float sum = 0.f;
      for (int t2=0;t2<30;++t2) sum += awL[b][t2]*(float)encOutL[b][t2][dl];
      float sn = __shfl_down(sum, 1);
      if (!(dl & 1))
        ast(CTXu + ((size_t)cur*4 + b)*512 + ((hc0 + dl) >> 1), packbf(sum, sn));
    }
    // batched poll ctxv -> ctxvL
    {
      u32x4 q0, q1;
      poll4x2((const char*)CTXB + (size_t)cur*8192 + tid*32, q0, q1);
      u32x4* dst = (u32x4*)((char*)&ctxvL[0][0] + (tid>>6)*2112 + (tid&63)*32);
      dst[0] = q0; dst[1] = q1;
    }
    __syncthreads();
    // P2: comb (own 16 out cols), K split across 4 waves
    {
      f32x4 acc = {0.f,0.f,0.f,0.f};
#pragma unroll
      for (int i = 0; i < 9; ++i){
        if (i < nkt){
          bf16x8 a = dfrag(&ctxvL[0][0], inpL, row, kt0c+i, kc, 1056);
          acc = MFMA(a, combF[i], acc);
        }
      }
      if (ln < 16){
#pragma unroll
        for (int r=0;r<4;++r) combL[w][r][ln] = acc[r];
      }
    }
    __syncthreads();
    if (tid < 64){
      int r = tid >> 4, l = tid & 15, col = slot*16 + l;
      float x = combL[0][r][l] + combL[1][r][l] + combL[2][r][l] + combL[3][r][l] + cbL[l];
      x = fmaxf(x, 0.0f);
      float xn = __shfl_down(x, 1);
      if (!(l & 1))
        ast(XBu + ((size_t)cur*4 + r)*256 + (col >> 1), packbf(x, xn));
    }
    // batched poll x -> xL (256 threads x 16B = 4KB)
    {
      u32x4 v = poll4((const char*)XB + (size_t)cur*4096 + tid*16);
      u32x4* dst = (u32x4*)((char*)&xL[0][0] + (tid>>6)*1056 + (tid&63)*16);
      dst[0] = v;
    }
    __syncthreads();
    // P3: w1-3 gi MFMA (A from xL, B from giL)
    if (w >= 1){
      int gate = w - 1;
      f32x4 a0 = {0.f,0.f,0.f,0.f}, a1 = {0.f,0.f,0.f,0.f};
#pragma unroll
      for (int kt = 0; kt < 16; ++kt){
        int k = kt*32 + kc;
        bf16x8 a = (row < 4) ? ld8(&xL[row][k]) : bzero8();
        int r0 = gate*32 + row, r1 = r0 + 16;
        bf16x8 b0 = ld8((__bf16*)((char*)giL + ((r0*1024 + k*2) ^ ((r0 & 7) << 4))));
        bf16x8 b1 = ld8((__bf16*)((char*)giL + ((r1*1024 + k*2) ^ ((r1 & 7) << 4))));
        a0 = MFMA(a, b0, a0);
        a1 = MFMA(a, b1, a1);
      }
      if (ln < 16){
#pragma unroll
        for (int r=0;r<4;++r){
          giO[gate][r][ln] = a0[r] + biL[gate][ln];
          giO[gate][r][16+ln] = a1[r] + biL[gate][16+ln];
        }
      }
    }
    __syncthreads();
    // GRU cell (own 32 cols)
    if (tid < 128){
      int b = tid >> 5, l = tid & 31, hcg = hc0 + l;
      float rr = sigf(giO[0][b][l] + ghL[0][b][l] + bhL[0][l]);
      float zz = sigf(giO[1][b][l] + ghL[1][b][l] + bhL[1][l]);
      float nn = tanhf(giO[2][b][l] + rr*(ghL[2][b][l] + bhL[2][l]));
      float hnew = (1.0f - zz)*nn + zz*hold;
      hold = hnew;
      float h2 = __shfl_down(hnew, 1);
      if (!(l & 1))
        ast(HBu + ((size_t)nxt*4 + b)*512 + (hcg >> 1), packbf(hnew, h2));
    }
  }
}

// ---------------- host ----------------
static const size_t O_BAR   = 0;
static const size_t O_XSB   = 12288;
static const size_t O_WCATP = 1486848;
static const size_t O_BIASC = 3715072;
static const size_t O_HENC  = 3723264;
static const size_t O_CENC  = 5689344;
static const size_t O_CTX   = 9621504;
static const size_t O_WIHPF = 13553664;
static const size_t O_WIHPB = 21942272;
static const size_t O_BSUM  = 30330880;
static const size_t O_XPF   = 30347264;
static const size_t O_XPB   = 38211584;
static const size_t O_HPYR  = 46075904;   // one layer region [2][4][4][512] bf16 = 32KB
static const size_t O_OUTA  = 46108672;
static const size_t O_OUTB  = 48074752;
static const size_t O_ENCO  = 49057792;
static const size_t O_H0F   = 49549312;
static const size_t O_HB    = 49565696;
static const size_t O_CTXB  = 49598464;
static const size_t O_XB    = 49631232;
static const size_t O_ATTNP = 49647616;
static const size_t O_COMBP = 49715200;
// end 50796544 (~48.4 MiB)

extern "C" void kernel_launch(void* const* d_in, const int* in_sizes, int n_in,
                              void* d_out, int out_size, void* d_ws, size_t ws_size,
                              hipStream_t stream)
{
  const float* xs    = (const float*)d_in[0];
  const int*   xlen  = (const int*)d_in[1];
  const float* eWih  = (const float*)d_in[2];
  const float* eWhh  = (const float*)d_in[3];
  const float* ebih  = (const float*)d_in[4];
  const float* ebhh  = (const float*)d_in[5];
  const float* pWihF = (const float*)d_in[6];
  const float* pWhhF = (const float*)d_in[7];
  const float* pbihF = (const float*)d_in[8];
  const float* pbhhF = (const float*)d_in[9];
  const float* pWihB = (const float*)d_in[10];
  const float* pWhhB = (const float*)d_in[11];
  const float* pbihB = (const float*)d_in[12];
  const float* pbhhB = (const float*)d_in[13];
  const float* attnW = (const float*)d_in[14];
  const float* attnb = (const float*)d_in[15];
  const float* combW = (const float*)d_in[16];
  const float* combb = (const float*)d_in[17];
  const float* gWih  = (const float*)d_in[18];
  const float* gWhh  = (const float*)d_in[19];
  const float* gbih  = (const float*)d_in[20];
  const float* gbhh  = (const float*)d_in[21];
  const float* outW  = (const float*)d_in[22];
  const float* outb  = (const float*)d_in[23];

  char* ws = (char*)d_ws;
  unsigned* BARU  = (unsigned*)(ws + O_BAR);
  __bf16* XSB     = (__bf16*)(ws + O_XSB);
  __bf16* WCATP   = (__bf16*)(ws + O_WCATP);
  float*  BIASC   = (float*)(ws + O_BIASC);
  __bf16* HENC    = (__bf16*)(ws + O_HENC);
  float*  CENC    = (float*)(ws + O_CENC);
  __bf16* CTX     = (__bf16*)(ws + O_CTX);
  __bf16* WIHPF   = (__bf16*)(ws + O_WIHPF);
  __bf16* WIHPB   = (__bf16*)(ws + O_WIHPB);
  float*  BSUM    = (float*)(ws + O_BSUM);
  float*  XPF     = (float*)(ws + O_XPF);
  float*  XPB     = (float*)(ws + O_XPB);
  __bf16* HPYR    = (__bf16*)(ws + O_HPYR);
  __bf16* OUTA    = (__bf16*)(ws + O_OUTA);
  __bf16* OUTB    = (__bf16*)(ws + O_OUTB);
  float*  ENCO    = (float*)(ws + O_ENCO);
  float*  H0F     = (float*)(ws + O_H0F);
  __bf16* HB      = (__bf16*)(ws + O_HB);
  __bf16* CTXB    = (__bf16*)(ws + O_CTXB);
  __bf16* XB      = (__bf16*)(ws + O_XB);
  __bf16* ATTNP   = (__bf16*)(ws + O_ATTNP);
  __bf16* COMBP   = (__bf16*)(ws + O_COMBP);

  initK<<<84, 256, 0, stream>>>(BARU, (unsigned*)HB, (unsigned*)CTXB, (unsigned*)XB);
  packSmallK<<<1193, 256, 0, stream>>>(xs, eWih, eWhh, ebih, ebhh, attnW, combW,
      XSB, WCATP, BIASC, ATTNP, COMBP);

  for (int t = 0; t < 12; ++t)
    encStepK<<<dim3(30, 8), 256, 0, stream>>>(XSB, HENC, CENC, WCATP, BIASC, xlen, CTX, t);

  const int Ts[4] = {240, 120, 60, 30};
  const __bf16* ins[4] = {CTX, OUTA, OUTB, OUTA};
  __bf16* outs[4] = {OUTA, OUTB, OUTA, OUTB};
  for (int L = 0; L < 4; ++L){
    int T = Ts[L];
    packPencK<<<4145, 256, 0, stream>>>(pWihF + (long)L*2048*2048, pWihB + (long)L*2048*2048,
        pbihF + L*2048, pbhhF + L*2048, pbihB + L*2048, pbhhB + L*2048,
        WIHPF, WIHPB, BSUM, (unsigned*)HPYR);
    int MB = (4*T + 63)/64;
    pencInK<<<dim3(MB, 8, 2), 1024, 0, stream>>>(ins[L], WIHPF, WIHPB, BSUM, XPF, XPB, 4*T);
    pyrRecK<<<32, 256, 0, stream>>>(pWhhF + (long)L*2048*512, pWhhB + (long)L*2048*512,
        XPF, XPB, HPYR, outs[L], ENCO, H0F, HB, T, (L==3) ? 1 : 0);
  }

  decoderK<<<32, 256, 0, stream>>>(gWih, gWhh, gbih, gbhh, combb, attnb, outW, outb,
      ATTNP, COMBP, ENCO, H0F, HB, CTXB, XB, (float*)d_out);
}

// Round 6
// 2116.930 us; speedup vs baseline: 783.0093x; 1.0658x over previous
//
#include <hip/hip_runtime.h>
#include <stdint.h>

typedef __attribute__((ext_vector_type(8))) __bf16 bf16x8;
typedef __attribute__((ext_vector_type(4))) float f32x4;
typedef __attribute__((ext_vector_type(4))) unsigned u32x4;

#define DEVI static __device__ __forceinline__
#define SENT 0xFFFFFFFFu

DEVI bf16x8 bzero8(){ bf16x8 r;
#pragma unroll
  for (int i=0;i<8;++i) r[i]=(__bf16)0.0f; return r; }

DEVI bf16x8 ld8(const __bf16* p){ return *(const bf16x8*)p; }
DEVI void st8(__bf16* p, bf16x8 v){ *(bf16x8*)p = v; }

DEVI f32x4 MFMA(bf16x8 a, bf16x8 b, f32x4 c){
  return __builtin_amdgcn_mfma_f32_16x16x32_bf16(a, b, c, 0, 0, 0);
}

DEVI float sigf(float x){ return 1.0f/(1.0f+__expf(-x)); }

// ---- agent-scope (MALL) relaxed atomics ----
DEVI void ast(unsigned* p, unsigned v){ __hip_atomic_store(p, v, __ATOMIC_RELAXED, __HIP_MEMORY_SCOPE_AGENT); }

DEVI unsigned packbf(float a, float b){
  union { __bf16 h[2]; unsigned u; } x; x.h[0]=(__bf16)a; x.h[1]=(__bf16)b; return x.u;
}
DEVI float bflo(unsigned u){ return __builtin_bit_cast(float, u<<16); }
DEVI float bfhi(unsigned u){ return __builtin_bit_cast(float, u & 0xffff0000u); }

DEVI unsigned bad4(u32x4 v){ return (v[0]==SENT)|(v[1]==SENT)|(v[2]==SENT)|(v[3]==SENT); }

// agent-coherent 16B load (bypass L1+L2, read MALL)
DEVI u32x4 ald4(const void* p){
  u32x4 v;
  asm volatile("global_load_dwordx4 %0, %1, off sc0 sc1\n\ts_waitcnt vmcnt(0)"
               : "=&v"(v) : "v"(p) : "memory");
  return v;
}
DEVI u32x4 poll4(const void* p){
  u32x4 v = ald4(p);
  while (bad4(v)){ __builtin_amdgcn_s_sleep(1); v = ald4(p); }
  return v;
}
DEVI void ald4x2(const void* p, u32x4& a, u32x4& b){
  asm volatile("global_load_dwordx4 %0, %2, off sc0 sc1\n\t"
               "global_load_dwordx4 %1, %2, off offset:16 sc0 sc1\n\t"
               "s_waitcnt vmcnt(0)"
               : "=&v"(a), "=&v"(b) : "v"(p) : "memory");
}
DEVI void poll4x2(const void* p, u32x4& a, u32x4& b){
  ald4x2(p, a, b);
  while (bad4(a) | bad4(b)){ __builtin_amdgcn_s_sleep(1); ald4x2(p, a, b); }
}

// ---------------- packing ----------------
DEVI void packGroup(const float* W, int Nsrc, int Kreal, int NT, __bf16* dst, long g){
  int kt = (int)(g / (NT*64));
  int rem = (int)(g % (NT*64));
  int nt = rem >> 6, ln = rem & 63;
  int row = nt*16 + (ln & 15);
  int col = kt*32 + ((ln >> 4) << 3);
  bf16x8 v = bzero8();
  if (row < Nsrc){
#pragma unroll
    for (int j=0;j<8;++j){ int c = col + j; if (c < Kreal) v[j] = (__bf16)W[(long)row*Kreal + c]; }
  }
  st8(dst + g*8, v);
}

DEVI void packGroupCat(const float* Wih, const float* Whh, __bf16* dst, long g){
  int kt = (int)(g / (128*64));
  int rem = (int)(g % (128*64));
  int nt = rem >> 6, ln = rem & 63;
  int prow = nt*16 + (ln & 15);
  int src = (prow & 3)*512 + (prow >> 2);
  int col = kt*32 + ((ln >> 4) << 3);
  bf16x8 v;
  if (col < 32){
#pragma unroll
    for (int j=0;j<8;++j) v[j] = (__bf16)Wih[(long)src*32 + col + j];
  } else {
#pragma unroll
    for (int j=0;j<8;++j) v[j] = (__bf16)Whh[(long)src*512 + (col-32) + j];
  }
  st8(dst + g*8, v);
}

// sentinel decoder comm buffers
__global__ void initK(unsigned* bar, unsigned* hb, unsigned* ctx, unsigned* xb){
  int g = blockIdx.x*256 + threadIdx.x;
  if (g < 3072){ bar[g] = 0u; return; }
  g -= 3072;
  if (g < 6144){ hb[2048 + g] = SENT; return; }   // HB bufs 1..3 (buf0 = h0b)
  g -= 6144;
  if (g < 8192){ ctx[g] = SENT; return; }
  g -= 8192;
  if (g < 4096){ xb[g] = SENT; return; }
}

__global__ void packSmallK(const float* __restrict__ xs, const float* __restrict__ eWih,
    const float* __restrict__ eWhh, const float* __restrict__ ebih, const float* __restrict__ ebhh,
    const float* __restrict__ attnW, const float* __restrict__ combW,
    __bf16* __restrict__ xsb, __bf16* __restrict__ wcatp, float* __restrict__ biasc,
    __bf16* __restrict__ attnp, __bf16* __restrict__ combp)
{
  long g = (long)blockIdx.x*blockDim.x + threadIdx.x;
  const long nWcat = 17L*128*64;
  const long nXs   = 92160;
  const long nBias = 2048;
  const long nAttn = 33L*2*64;
  const long nComb = 33L*32*64;
  if (g < nWcat){ packGroupCat(eWih, eWhh, wcatp, g); return; }
  g -= nWcat;
  if (g < nXs){
    const float* s = xs + g*8; bf16x8 v;
#pragma unroll
    for (int j=0;j<8;++j) v[j] = (__bf16)s[j];
    st8(xsb + g*8, v); return;
  }
  g -= nXs;
  if (g < nBias){ int src = ((int)g & 3)*512 + ((int)g >> 2); biasc[g] = ebih[src] + ebhh[src]; return; }
  g -= nBias;
  if (g < nAttn){ packGroup(attnW, 30, 1032, 2, attnp, g); return; }
  g -= nAttn;
  if (g < nComb){ packGroup(combW, 512, 1032, 32, combp, g); return; }
}

// pack pyramid layer: Wih (MFMA-B layout), biases, HPYR sentinel init,
// and Whh -> per-(dir,slot,wave) register-fragment layout (bf16)
__global__ void packPencK(const float* __restrict__ Wf, const float* __restrict__ Wb,
    const float* __restrict__ WhF, const float* __restrict__ WhB,
    const float* __restrict__ bihf, const float* __restrict__ bhhf,
    const float* __restrict__ bihb, const float* __restrict__ bhhb,
    __bf16* __restrict__ pf, __bf16* __restrict__ pb, float* __restrict__ bsum,
    __bf16* __restrict__ pwhh, unsigned* __restrict__ hpy)
{
  long g = (long)blockIdx.x*blockDim.x + threadIdx.x;
  const long nW = 64L*128*64;
  if (g < nW){ packGroup(Wf, 2048, 2048, 128, pf, g); return; }
  g -= nW;
  if (g < nW){ packGroup(Wb, 2048, 2048, 128, pb, g); return; }
  g -= nW;
  if (g < 2048){ bsum[g] = bihf[g] + bhhf[g]; return; }
  g -= 2048;
  if (g < 2048){ bsum[2048+g] = bihb[g] + bhhb[g]; return; }
  g -= 2048;
  if (g < 8192){  // [2dir][4buf][4][512] bf16 = 8192 dwords; buf0=0, bufs1-3=SENT
    hpy[g] = ((g >> 10) & 3) ? SENT : 0u;
    return;
  }
  g -= 8192;
  if (g < 262144){
    int lane = (int)(g & 63);
    int f    = (int)((g >> 6) & 31);
    int w    = (int)((g >> 11) & 3);
    int slot = (int)((g >> 13) & 15);
    int dir  = (int)((g >> 17) & 1);
    int kt = f >> 1, nt = f & 1;
    int row16 = lane & 15, kch = lane >> 4;
    int srow = w*512 + slot*32 + nt*16 + row16;   // gate w, col slot*32 + nt*16 + row16
    int scol = kt*32 + kch*8;
    const float* W = dir ? WhB : WhF;
    bf16x8 v;
#pragma unroll
    for (int j=0;j<8;++j) v[j] = (__bf16)W[(long)srow*512 + scol + j];
    st8(pwhh + g*8, v);
  }
}

// ---------------- encoder step ----------------
__global__ __launch_bounds__(256, 1) void encStepK(
    const __bf16* __restrict__ xsb,
    __bf16* __restrict__ henc,
    float* __restrict__ cenc,
    const __bf16* __restrict__ wcatp,
    const float* __restrict__ biasc,
    const int* __restrict__ xlen,
    __bf16* __restrict__ ctx,
    int t)
{
  __shared__ float glds[64][260];
  const int tid = threadIdx.x;
  const int w = tid >> 6, ln = tid & 63;
  const int m0 = blockIdx.x * 64;
  const int nb = blockIdx.y;
  f32x4 acc[16];
#pragma unroll
  for (int i=0;i<16;++i) acc[i] = (f32x4){0.f,0.f,0.f,0.f};

  const int arow = m0 + w*16 + (ln & 15);
  const int kc = (ln >> 4) << 3;
  const int ktEnd = (t == 0) ? 1 : 17;
  for (int kt = 0; kt < ktEnd; ++kt){
    bf16x8 a;
    if (kt == 0) a = ld8(xsb + ((long)t*1920 + arow)*32 + kc);
    else         a = ld8(henc + (long)arow*512 + (kt-1)*32 + kc);
    const __bf16* bp = wcatp + (((long)kt*128 + nb*16)*64 + ln)*8;
#pragma unroll
    for (int n2 = 0; n2 < 16; ++n2){
      bf16x8 b = ld8(bp + (long)n2*512);
      acc[n2] = MFMA(a, b, acc[n2]);
    }
  }
  const int r4 = (ln >> 4) << 2;
#pragma unroll
  for (int n2 = 0; n2 < 16; ++n2){
#pragma unroll
    for (int r = 0; r < 4; ++r)
      glds[w*16 + r4 + r][n2*16 + (ln & 15)] = acc[n2][r];
  }
  __syncthreads();
  for (int it = 0; it < 16; ++it){
    int idx = tid + it*256;
    int mrow = idx >> 6, hcl = idx & 63;
    int n = m0 + mrow;
    int hcg = nb*64 + hcl;
    float ig = glds[mrow][hcl*4+0] + biasc[nb*256 + hcl*4+0];
    float fg = glds[mrow][hcl*4+1] + biasc[nb*256 + hcl*4+1];
    float gg = glds[mrow][hcl*4+2] + biasc[nb*256 + hcl*4+2];
    float og = glds[mrow][hcl*4+3] + biasc[nb*256 + hcl*4+3];
    float c_old = (t == 0) ? 0.0f : cenc[(long)n*512 + hcg];
    float cn = sigf(fg)*c_old + sigf(ig)*tanhf(gg);
    float h  = sigf(og)*tanhf(cn);
    cenc[(long)n*512 + hcg] = cn;
    henc[(long)n*512 + hcg] = (__bf16)h;
    if (xlen[n] - 1 == t){
      ctx[(long)n*1024 + hcg]       = (__bf16)h;
      ctx[(long)n*1024 + 512 + hcg] = (__bf16)cn;
    }
  }
}

// ---------------- pyramid input GEMM ----------------
__global__ __launch_bounds__(1024) void pencInK(
   const __bf16* __restrict__ inb,
   const __bf16* __restrict__ wpf, const __bf16* __restrict__ wpb,
   const float* __restrict__ bsum,
   float* __restrict__ xpf, float* __restrict__ xpb,
   int M)
{
  const int tid = threadIdx.x, ln = tid & 63, wv = tid >> 6;
  const int rg = wv >> 2, cg = wv & 3;
  const int dir = blockIdx.z;
  const int m0 = blockIdx.x*64 + rg*16;
  const int nb = blockIdx.y;
  const __bf16* wp = dir ? wpb : wpf;
  float* xp = dir ? xpb : xpf;
  const float* bs = bsum + dir*2048;
  f32x4 acc[4];
#pragma unroll
  for (int i=0;i<4;++i) acc[i] = (f32x4){0.f,0.f,0.f,0.f};
  const int arow = m0 + (ln & 15);
  const int kc = (ln >> 4) << 3;
  const bool aok = arow < M;
  for (int kt = 0; kt < 64; ++kt){
    bf16x8 a = aok ? ld8(inb + (long)arow*2048 + kt*32 + kc) : bzero8();
    const __bf16* bp = wp + (((long)kt*128 + nb*16 + cg*4)*64 + ln)*8;
#pragma unroll
    for (int q = 0; q < 4; ++q){
      bf16x8 b = ld8(bp + (long)q*512);
      acc[q] = MFMA(a, b, acc[q]);
    }
  }
  const int r4 = (ln >> 4) << 2;
#pragma unroll
  for (int q = 0; q < 4; ++q){
    int col = (nb*16 + cg*4 + q)*16 + (ln & 15);
#pragma unroll
    for (int r = 0; r < 4; ++r){
      int rowo = m0 + r4 + r;
      if (rowo < M) xp[(long)rowo*2048 + col] = acc[q][r] + bs[col];
    }
  }
}

// ---------------- pyramid recurrence: persistent, register-B, sentinel poll ----------------
// 32 blocks: [0..15]=fwd, [16..31]=bwd; hbuf = this layer's [2dir][4buf][4][512]
__global__ __launch_bounds__(256, 1) void pyrRecK(
  const __bf16* __restrict__ pwhh,   // packed [2dir][16slot][4w][32frag][64lane][8]
  const float* __restrict__ xpf, const float* __restrict__ xpb,
  __bf16* __restrict__ hbuf,
  __bf16* __restrict__ outb,
  float* __restrict__ outf,
  float* __restrict__ h0f, __bf16* __restrict__ h0b,
  int T, int isLast)
{
  __shared__ __align__(16) __bf16 hsL[2][4*512];
  __shared__ float glds[4][4][32];
  const int tid = threadIdx.x, ln = tid & 63, w = tid >> 6;
  const int bk = blockIdx.x;
  const int dir = bk >> 4, slot = bk & 15;
  const int hc0 = slot * 32;
  const float* xp = dir ? xpb : xpf;
  unsigned* hbu = (unsigned*)hbuf;

  // time-invariant Whh B-fragments -> registers (coalesced packed reads)
  bf16x8 BF[32];
  {
    const __bf16* wb = pwhh + ((((size_t)(dir*16 + slot)*4 + w)*32)*64 + ln)*8;
#pragma unroll
    for (int f = 0; f < 32; ++f) BF[f] = ld8(wb + (size_t)f*512);
  }

  const int arow = ln & 15;
  const int kc = (ln >> 4) << 3;
  float cv = 0.0f;
  // x(0) prefetch
  float x0=0.f,x1=0.f,x2=0.f,x3=0.f;
  if (tid < 128){
    int pos0 = dir ? (T-1) : 0;
    const float* xr = xp + ((size_t)((tid>>5)*T + pos0))*2048 + hc0 + (tid & 31);
    x0 = xr[0]; x1 = xr[512]; x2 = xr[1024]; x3 = xr[1536];
  }

  for (int t = 0; t < T; ++t){
    int cur = t & 3, nxt = (t+1) & 3, clr = (t+2) & 3;
    int pos = dir ? (T-1-t) : t;
    // poll h(t) -> hsL[t&1]; nothing else shares this vmcnt window
    {
      u32x4 v = poll4((const char*)hbuf + (size_t)(dir*4 + cur)*4096 + tid*16);
      ((u32x4*)hsL[t & 1])[tid] = v;
    }
    __syncthreads();
    // re-sentinel buffer t+2 (own cols) — now off the poll path
    if (tid < 64){
      int b = tid >> 4, i = tid & 15;
      ast(hbu + ((size_t)(dir*4 + clr)*4 + b)*256 + (hc0 >> 1) + i, SENT);
    }
    // MFMA with register-resident B
    const __bf16* hs = hsL[t & 1];
    f32x4 a0 = {0.f,0.f,0.f,0.f}, a1 = {0.f,0.f,0.f,0.f};
#pragma unroll
    for (int kt = 0; kt < 16; ++kt){
      bf16x8 a = (arow < 4) ? ld8(hs + arow*512 + kt*32 + kc) : bzero8();
      a0 = MFMA(a, BF[kt*2+0], a0);
      a1 = MFMA(a, BF[kt*2+1], a1);
    }
    // prefetch x(t+1) — hidden under glds/cell
    float xn0=0.f,xn1=0.f,xn2=0.f,xn3=0.f;
    if (t+1 < T && tid < 128){
      int pos2 = dir ? (T-2-t) : (t+1);
      const float* xr = xp + ((size_t)((tid>>5)*T + pos2))*2048 + hc0 + (tid & 31);
      xn0 = xr[0]; xn1 = xr[512]; xn2 = xr[1024]; xn3 = xr[1536];
    }
    if (ln < 16){
#pragma unroll
      for (int r=0;r<4;++r){ glds[w][r][ln] = a0[r]; glds[w][r][16+ln] = a1[r]; }
    }
    __syncthreads();
    if (tid < 128){
      int b = tid >> 5, hcl = tid & 31, hcg = hc0 + hcl;
      float ig = glds[0][b][hcl] + x0;
      float fg = glds[1][b][hcl] + x1;
      float gg = glds[2][b][hcl] + x2;
      float og = glds[3][b][hcl] + x3;
      cv = sigf(fg)*cv + sigf(ig)*tanhf(gg);
      float h = sigf(og)*tanhf(cv);
      float hn = __shfl_down(h, 1);
      if (!(hcl & 1))
        ast(hbu + ((size_t)(dir*4 + nxt)*4 + b)*256 + (hcg >> 1), packbf(h, hn));
      if (!isLast){
        outb[((long)(b*T + pos))*1024 + dir*512 + hcg] = (__bf16)h;
      } else {
        outf[((long)(b*T + pos))*1024 + dir*512 + hcg] = h;
        if (t == T-1){
          h0f[b*1024 + dir*512 + hcg] = h;
          h0b[b*1024 + dir*512 + hcg] = (__bf16)h;
        }
      }
    }
    x0=xn0; x1=xn1; x2=xn2; x3=xn3;
  }
}

// ---------------- decoder: persistent, 32 blocks, sentinel data-poll ----------------
DEVI bf16x8 dfrag(const __bf16* base, const __bf16* inp, int row, int kt, int kc, int stride){
  if (row >= 4) return bzero8();
  int k = kt*32 + kc;
  if (k == 0) return ld8(inp + row*8);
  int off = k - 8;
  return (off < 1024) ? ld8(base + row*stride + off) : bzero8();
}

__global__ __launch_bounds__(256, 1) void decoderK(
  const float* __restrict__ gWih,   // [3072][512]
  const float* __restrict__ gWhh,   // [3072][1024]
  const float* __restrict__ gbih, const float* __restrict__ gbhh,
  const float* __restrict__ combBias, const float* __restrict__ attnBias,
  const float* __restrict__ outW, const float* __restrict__ outBias,
  const __bf16* __restrict__ attnP, const __bf16* __restrict__ combP,
  const float* __restrict__ encOut,  // [4][30][1024] f32
  const float* __restrict__ h0f,
  __bf16* __restrict__ HB,           // [4buf][4][1024]
  __bf16* __restrict__ CTXB,         // [4buf][4][1024]
  __bf16* __restrict__ XB,           // [4buf][4][512]
  float* __restrict__ dout)
{
  __shared__ __align__(16) __bf16 giL[96*512];     // 96 KB
  __shared__ __align__(16) __bf16 outWL[8*1024];
  __shared__ __align__(16) __bf16 hL[4*1024];
  __shared__ __align__(16) __bf16 ctxvL[4][1056];
  __shared__ __align__(16) __bf16 xL[4][528];
  __shared__ __bf16 encOutL[4][30][32];
  __shared__ __align__(16) __bf16 inpL[32];
  __shared__ float awL[4][30];
  __shared__ float redL[4][8];
  __shared__ float ghL[3][4][32];
  __shared__ float giO[3][4][32];
  __shared__ float combL[4][4][16];
  __shared__ float biL[3][32], bhL[3][32];
  __shared__ float abL[30], cbL[16];

  const int tid = threadIdx.x, ln = tid & 63, w = tid >> 6;
  const int slot = blockIdx.x;
  const int hc0 = slot * 32;
  unsigned* HBu = (unsigned*)HB;
  unsigned* CTXu = (unsigned*)CTXB;
  unsigned* XBu = (unsigned*)XB;

  // gi weights -> LDS (3 gates x 32 own cols = 96 rows x 512, XOR swizzled)
  for (int it = 0; it < 24; ++it){
    int g = it*256 + tid;
    int rho = g >> 6, c8 = g & 63;
    int gate = rho >> 5, r = rho & 31;
    const float* s = gWih + ((long)(gate*1024 + hc0 + r))*512 + c8*8;
    bf16x8 v;
#pragma unroll
    for (int j=0;j<8;++j) v[j] = (__bf16)s[j];
    st8((__bf16*)((char*)giL + ((rho*1024 + c8*16) ^ ((rho & 7) << 4))), v);
  }
  for (int it = 0; it < 32; ++it){
    int g = it*256 + tid;
    outWL[g] = (__bf16)outW[g];
  }
  for (int idx = tid; idx < 3840; idx += 256){
    int b = idx/960, rem = idx%960;
    int t2 = rem >> 5, dl = rem & 31;
    encOutL[b][t2][dl] = (__bf16)encOut[((long)b*30 + t2)*1024 + hc0 + dl];
  }
  if (tid < 96){
    int g2 = tid >> 5, l = tid & 31;
    biL[g2][l] = gbih[g2*1024 + hc0 + l];
    bhL[g2][l] = gbhh[g2*1024 + hc0 + l];
  }
  if (tid < 30) abL[tid] = attnBias[tid];
  if (tid < 16) cbL[tid] = combBias[slot*16 + tid];

  const int row = ln & 15, kc = (ln >> 4) << 3;
  // bigF: w0 -> attn frags [2x33]; w1-3 -> gh frags for gate w-1 [2x32]
  bf16x8 bigF[66];
  if (w == 0){
#pragma unroll
    for (int nt = 0; nt < 2; ++nt)
#pragma unroll
      for (int kt = 0; kt < 33; ++kt)
        bigF[nt*33 + kt] = ld8(attnP + (((size_t)kt*2 + nt)*64 + ln)*8);
  } else {
    int gate = w - 1;
#pragma unroll
    for (int nt = 0; nt < 2; ++nt)
#pragma unroll
      for (int kt = 0; kt < 32; ++kt){
        const float* s = gWhh + ((long)(gate*1024 + hc0 + nt*16 + row))*1024 + kt*32 + kc;
        bf16x8 v;
#pragma unroll
        for (int j=0;j<8;++j) v[j] = (__bf16)s[j];
        bigF[nt*33 + kt] = v;
      }
  }
  const int kt0c = (w == 0) ? 0 : (w*8 + 1);
  const int nkt = (w == 0) ? 9 : 8;
  bf16x8 combF[9];
#pragma unroll
  for (int i = 0; i < 9; ++i)
    combF[i] = (i < nkt) ? ld8(combP + (((size_t)(kt0c+i)*32 + slot)*64 + ln)*8) : bzero8();

  float hold = 0.f;
  if (tid < 128) hold = h0f[(tid>>5)*1024 + hc0 + (tid & 31)];
  __syncthreads();

  for (int s = 0; s <= 32; ++s){
    int cur = s & 3, nxt = (s+1) & 3, clr = (s+2) & 3;
    // batched poll h(s) -> hL (256 threads x 32B = 8KB); clean vmcnt window
    {
      u32x4 q0, q1;
      poll4x2((const char*)HB + (size_t)cur*8192 + tid*32, q0, q1);
      ((u32x4*)hL)[tid*2]   = q0;
      ((u32x4*)hL)[tid*2+1] = q1;
    }
    __syncthreads();
    // re-sentinel step s+2 buffers (own cols) — after the poll
    if (tid < 64){
      int b = tid >> 4, i = tid & 15;
      ast(HBu  + ((size_t)clr*4 + b)*512 + (hc0 >> 1) + i, SENT);
      ast(CTXu + ((size_t)clr*4 + b)*512 + (hc0 >> 1) + i, SENT);
    }
    if (tid < 32){
      int b = tid >> 3, i = tid & 7;
      ast(XBu + ((size_t)clr*4 + b)*256 + ((slot*16) >> 1) + i, SENT);
    }
    if (s == 0){
      if (tid < 32) inpL[tid] = (__bf16)0.0f;
      __syncthreads();
    } else {
      int o = tid >> 3, sl = tid & 7;
      int b = o >> 3, l = o & 7;
      const unsigned* hlp = (const unsigned*)hL + b*512 + sl*64;
      const unsigned* wlp = (const unsigned*)outWL + l*512 + sl*64;
      float p = 0.f;
      for (int kk = 0; kk < 64; ++kk){
        unsigned u = hlp[kk], t2 = wlp[kk];
        p += bflo(u)*bflo(t2) + bfhi(u)*bfhi(t2);
      }
      p += __shfl_down(p, 4);
      p += __shfl_down(p, 2);
      p += __shfl_down(p, 1);
      if (sl == 0) redL[b][l] = p + outBias[l];
      __syncthreads();
      if (tid < 4){
        float m = redL[tid][0];
        for (int l2=1;l2<8;++l2) m = fmaxf(m, redL[tid][l2]);
        float sum = 0.f;
        for (int l2=0;l2<8;++l2) sum += __expf(redL[tid][l2]-m);
        float lse = m + __logf(sum);
        for (int l2=0;l2<8;++l2){
          float lp = redL[tid][l2] - lse;
          inpL[tid*8 + l2] = (__bf16)lp;
          if (slot == 0) dout[((long)tid*32 + (s-1))*8 + l2] = lp;
        }
      }
      __syncthreads();
    }
    if (s == 32) break;

    // P1: w0 attn logits; w1-3 gh (gate w-1), B in registers
    if (w == 0){
      f32x4 a0 = {0.f,0.f,0.f,0.f}, a1 = {0.f,0.f,0.f,0.f};
#pragma unroll
      for (int kt = 0; kt < 33; ++kt){
        bf16x8 a = dfrag(hL, inpL, row, kt, kc, 1024);
        a0 = MFMA(a, bigF[kt], a0);
        a1 = MFMA(a, bigF[33+kt], a1);
      }
      if (ln < 16){
#pragma unroll
        for (int r=0;r<4;++r) awL[r][ln] = a0[r] + abL[ln];
        if (16 + ln < 30){
#pragma unroll
          for (int r=0;r<4;++r) awL[r][16+ln] = a1[r] + abL[16+ln];
        }
      }
    } else {
      f32x4 a0 = {0.f,0.f,0.f,0.f}, a1 = {0.f,0.f,0.f,0.f};
#pragma unroll
      for (int kt = 0; kt < 32; ++kt){
        int k = kt*32 + kc;
        bf16x8 a = (row < 4) ? ld8(hL + row*1024 + k) : bzero8();
        a0 = MFMA(a, bigF[kt], a0);
        a1 = MFMA(a, bigF[33+kt], a1);
      }
      if (ln < 16){
        int gate = w - 1;
#pragma unroll
        for (int r=0;r<4;++r){
          ghL[gate][r][ln] = a0[r];
          ghL[gate][r][16+ln] = a1[r];
        }
      }
    }
    __syncthreads();
    if (tid < 4){
      float m = awL[tid][0];
      for (int t2=1;t2<30;++t2) m = fmaxf(m, awL[tid][t2]);
      float sum = 0.f;
      for (int t2=0;t2<30;++t2){ float e = __expf(awL[tid][t2]-m); awL[tid][t2] = e; sum += e; }
      float inv = 1.0f/sum;
      for (int t2=0;t2<30;++t2) awL[tid][t2] *= inv;
    }
    __syncthreads();
    // produce ctxv (own 32 cols)
    if (tid < 128){
      int b = tid >> 5, dl = tid & 31;
      float sum = 0.f;
      for (int t2=0;t2<30;++t2) sum += awL[b][t2]*(float)encOutL[b][t2][dl];
      float sn = __shfl_down(sum, 1);
      if (!(dl & 1))
        ast(CTXu + ((size_t)cur*4 + b)*512 + ((hc0 + dl) >> 1), packbf(sum, sn));
    }
    // batched poll ctxv -> ctxvL
    {
      u32x4 q0, q1;
      poll4x2((const char*)CTXB + (size_t)cur*8192 + tid*32, q0, q1);
      u32x4* dst = (u32x4*)((char*)&ctxvL[0][0] + (tid>>6)*2112 + (tid&63)*32);
      dst[0] = q0; dst[1] = q1;
    }
    __syncthreads();
    // P2: comb (own 16 out cols), K split across 4 waves
    {
      f32x4 acc = {0.f,0.f,0.f,0.f};
#pragma unroll
      for (int i = 0; i < 9; ++i){
        if (i < nkt){
          bf16x8 a = dfrag(&ctxvL[0][0], inpL, row, kt0c+i, kc, 1056);
          acc = MFMA(a, combF[i], acc);
        }
      }
      if (ln < 16){
#pragma unroll
        for (int r=0;r<4;++r) combL[w][r][ln] = acc[r];
      }
    }
    __syncthreads();
    if (tid < 64){
      int r = tid >> 4, l = tid & 15, col = slot*16 + l;
      float x = combL[0][r][l] + combL[1][r][l] + combL[2][r][l] + combL[3][r][l] + cbL[l];
      x = fmaxf(x, 0.0f);
      float xn = __shfl_down(x, 1);
      if (!(l & 1))
        ast(XBu + ((size_t)cur*4 + r)*256 + (col >> 1), packbf(x, xn));
    }
    // batched poll x -> xL (256 threads x 16B = 4KB)
    {
      u32x4 v = poll4((const char*)XB + (size_t)cur*4096 + tid*16);
      u32x4* dst = (u32x4*)((char*)&xL[0][0] + (tid>>6)*1056 + (tid&63)*16);
      dst[0] = v;
    }
    __syncthreads();
    // P3: w1-3 gi MFMA (A from xL, B from giL)
    if (w >= 1){
      int gate = w - 1;
      f32x4 a0 = {0.f,0.f,0.f,0.f}, a1 = {0.f,0.f,0.f,0.f};
#pragma unroll
      for (int kt = 0; kt < 16; ++kt){
        int k = kt*32 + kc;
        bf16x8 a = (row < 4) ? ld8(&xL[row][k]) : bzero8();
        int r0 = gate*32 + row, r1 = r0 + 16;
        bf16x8 b0 = ld8((__bf16*)((char*)giL + ((r0*1024 + k*2) ^ ((r0 & 7) << 4))));
        bf16x8 b1 = ld8((__bf16*)((char*)giL + ((r1*1024 + k*2) ^ ((r1 & 7) << 4))));
        a0 = MFMA(a, b0, a0);
        a1 = MFMA(a, b1, a1);
      }
      if (ln < 16){
#pragma unroll
        for (int r=0;r<4;++r){
          giO[gate][r][ln] = a0[r] + biL[gate][ln];
          giO[gate][r][16+ln] = a1[r] + biL[gate][16+ln];
        }
      }
    }
    __syncthreads();
    // GRU cell (own 32 cols)
    if (tid < 128){
      int b = tid >> 5, l = tid & 31, hcg = hc0 + l;
      float rr = sigf(giO[0][b][l] + ghL[0][b][l] + bhL[0][l]);
      float zz = sigf(giO[1][b][l] + ghL[1][b][l] + bhL[1][l]);
      float nn = tanhf(giO[2][b][l] + rr*(ghL[2][b][l] + bhL[2][l]));
      float hnew = (1.0f - zz)*nn + zz*hold;
      hold = hnew;
      float h2 = __shfl_down(hnew, 1);
      if (!(l & 1))
        ast(HBu + ((size_t)nxt*4 + b)*512 + (hcg >> 1), packbf(hnew, h2));
    }
  }
}

// ---------------- host ----------------
static const size_t O_BAR   = 0;
static const size_t O_XSB   = 12288;
static const size_t O_WCATP = 1486848;
static const size_t O_BIASC = 3715072;
static const size_t O_HENC  = 3723264;
static const size_t O_PWHH  = 3723264;    // reuses HENC+CENC region after encoder
static const size_t O_CENC  = 5689344;
static const size_t O_CTX   = 9621504;
static const size_t O_WIHPF = 13553664;
static const size_t O_WIHPB = 21942272;
static const size_t O_BSUM  = 30330880;
static const size_t O_XPF   = 30347264;
static const size_t O_XPB   = 38211584;
static const size_t O_HPYR  = 46075904;   // [2][4][4][512] bf16 = 32KB
static const size_t O_OUTA  = 46108672;
static const size_t O_OUTB  = 48074752;
static const size_t O_ENCO  = 49057792;
static const size_t O_H0F   = 49549312;
static const size_t O_HB    = 49565696;
static const size_t O_CTXB  = 49598464;
static const size_t O_XB    = 49631232;
static const size_t O_ATTNP = 49647616;
static const size_t O_COMBP = 49715200;
// end 50796544 (~48.4 MiB)

extern "C" void kernel_launch(void* const* d_in, const int* in_sizes, int n_in,
                              void* d_out, int out_size, void* d_ws, size_t ws_size,
                              hipStream_t stream)
{
  const float* xs    = (const float*)d_in[0];
  const int*   xlen  = (const int*)d_in[1];
  const float* eWih  = (const float*)d_in[2];
  const float* eWhh  = (const float*)d_in[3];
  const float* ebih  = (const float*)d_in[4];
  const float* ebhh  = (const float*)d_in[5];
  const float* pWihF = (const float*)d_in[6];
  const float* pWhhF = (const float*)d_in[7];
  const float* pbihF = (const float*)d_in[8];
  const float* pbhhF = (const float*)d_in[9];
  const float* pWihB = (const float*)d_in[10];
  const float* pWhhB = (const float*)d_in[11];
  const float* pbihB = (const float*)d_in[12];
  const float* pbhhB = (const float*)d_in[13];
  const float* attnW = (const float*)d_in[14];
  const float* attnb = (const float*)d_in[15];
  const float* combW = (const float*)d_in[16];
  const float* combb = (const float*)d_in[17];
  const float* gWih  = (const float*)d_in[18];
  const float* gWhh  = (const float*)d_in[19];
  const float* gbih  = (const float*)d_in[20];
  const float* gbhh  = (const float*)d_in[21];
  const float* outW  = (const float*)d_in[22];
  const float* outb  = (const float*)d_in[23];

  char* ws = (char*)d_ws;
  unsigned* BARU  = (unsigned*)(ws + O_BAR);
  __bf16* XSB     = (__bf16*)(ws + O_XSB);
  __bf16* WCATP   = (__bf16*)(ws + O_WCATP);
  float*  BIASC   = (float*)(ws + O_BIASC);
  __bf16* HENC    = (__bf16*)(ws + O_HENC);
  __bf16* PWHH    = (__bf16*)(ws + O_PWHH);
  float*  CENC    = (float*)(ws + O_CENC);
  __bf16* CTX     = (__bf16*)(ws + O_CTX);
  __bf16* WIHPF   = (__bf16*)(ws + O_WIHPF);
  __bf16* WIHPB   = (__bf16*)(ws + O_WIHPB);
  float*  BSUM    = (float*)(ws + O_BSUM);
  float*  XPF     = (float*)(ws + O_XPF);
  float*  XPB     = (float*)(ws + O_XPB);
  __bf16* HPYR    = (__bf16*)(ws + O_HPYR);
  __bf16* OUTA    = (__bf16*)(ws + O_OUTA);
  __bf16* OUTB    = (__bf16*)(ws + O_OUTB);
  float*  ENCO    = (float*)(ws + O_ENCO);
  float*  H0F     = (float*)(ws + O_H0F);
  __bf16* HB      = (__bf16*)(ws + O_HB);
  __bf16* CTXB    = (__bf16*)(ws + O_CTXB);
  __bf16* XB      = (__bf16*)(ws + O_XB);
  __bf16* ATTNP   = (__bf16*)(ws + O_ATTNP);
  __bf16* COMBP   = (__bf16*)(ws + O_COMBP);

  initK<<<84, 256, 0, stream>>>(BARU, (unsigned*)HB, (unsigned*)CTXB, (unsigned*)XB);
  packSmallK<<<1193, 256, 0, stream>>>(xs, eWih, eWhh, ebih, ebhh, attnW, combW,
      XSB, WCATP, BIASC, ATTNP, COMBP);

  for (int t = 0; t < 12; ++t)
    encStepK<<<dim3(30, 8), 256, 0, stream>>>(XSB, HENC, CENC, WCATP, BIASC, xlen, CTX, t);

  const int Ts[4] = {240, 120, 60, 30};
  const __bf16* ins[4] = {CTX, OUTA, OUTB, OUTA};
  __bf16* outs[4] = {OUTA, OUTB, OUTA, OUTB};
  for (int L = 0; L < 4; ++L){
    int T = Ts[L];
    packPencK<<<5168, 256, 0, stream>>>(pWihF + (long)L*2048*2048, pWihB + (long)L*2048*2048,
        pWhhF + (long)L*2048*512, pWhhB + (long)L*2048*512,
        pbihF + L*2048, pbhhF + L*2048, pbihB + L*2048, pbhhB + L*2048,
        WIHPF, WIHPB, BSUM, PWHH, (unsigned*)HPYR);
    int MB = (4*T + 63)/64;
    pencInK<<<dim3(MB, 8, 2), 1024, 0, stream>>>(ins[L], WIHPF, WIHPB, BSUM, XPF, XPB, 4*T);
    pyrRecK<<<32, 256, 0, stream>>>(PWHH, XPF, XPB, HPYR, outs[L], ENCO, H0F, HB,
        T, (L==3) ? 1 : 0);
  }

  decoderK<<<32, 256, 0, stream>>>(gWih, gWhh, gbih, gbhh, combb, attnb, outW, outb,
      ATTNP, COMBP, ENCO, H0F, HB, CTXB, XB, (float*)d_out);
}